// Round 4
// baseline (484.980 us; speedup 1.0000x reference)
//
#include <hip/hip_runtime.h>
#include <hip/hip_bf16.h>
#include <math.h>

using bf16 = __hip_bfloat16;
typedef _Float16 hf;
typedef hf __attribute__((ext_vector_type(2))) hf2;
typedef __attribute__((ext_vector_type(8))) short short8;
typedef __attribute__((ext_vector_type(4))) float floatx4;

__device__ __forceinline__ float b2f(bf16 x){ return __bfloat162float(x); }
__device__ __forceinline__ bf16 f2b(float x){ return __float2bfloat16(x); }
__device__ __forceinline__ short bfbits(float x){ bf16 t = __float2bfloat16(x); return *(short*)&t; }
__device__ __forceinline__ short hfbits(float x){ hf t = (hf)x; return *(short*)&t; }
__device__ __forceinline__ hf2 u2h2(unsigned u){ return *(hf2*)&u; }

__global__ void fill_const(float* __restrict__ p, float v, int n){
  int i = blockIdx.x*blockDim.x + threadIdx.x;
  if (i < n) p[i] = v;
}

__global__ void conv_f2b(const float* __restrict__ src, bf16* __restrict__ dst, int n){
  int i = blockIdx.x*blockDim.x + threadIdx.x;
  if (i < n) dst[i] = f2b(src[i]);
}

__global__ void conv_f2h(const float* __restrict__ src, short* __restrict__ dst, int n){
  int i = blockIdx.x*blockDim.x + threadIdx.x;
  if (i < n) dst[i] = hfbits(src[i]);
}

// Wcat bf16 [384,256] = [Wq; Wk; Wv|0], bcat f32 [384]
__global__ void build_wcat(const float* __restrict__ Wq, const float* __restrict__ Wk,
                           const float* __restrict__ Wv, const float* __restrict__ bq,
                           const float* __restrict__ bk, const float* __restrict__ bv,
                           bf16* __restrict__ Wcat, float* __restrict__ bcat){
  int i = blockIdx.x*blockDim.x + threadIdx.x;
  if (i >= 384*256) return;
  int r = i >> 8, c = i & 255;
  float v;
  if (r < 128)       v = Wq[r*256 + c];
  else if (r < 256)  v = Wk[(r-128)*256 + c];
  else               v = (c < 128) ? Wv[(r-256)*128 + c] : 0.f;
  Wcat[i] = f2b(v);
  if (i < 384) bcat[i] = (i < 128) ? bq[i] : (i < 256 ? bk[i-128] : bv[i-256]);
}

// ---------------- CSR build ----------------
__global__ void edge_hist(const int* __restrict__ ei, int E, int* __restrict__ deg){
  int e = blockIdx.x*blockDim.x + threadIdx.x;
  if (e >= E) return;
  atomicAdd(&deg[ei[E + e]], 1);
}

// Hierarchical scan, stage 1: per-block (256-elem) reduce of deg -> bsum[block]
__global__ __launch_bounds__(256) void scan_p1(const int* __restrict__ deg, int Nn,
                                               int* __restrict__ bsum){
  int i = blockIdx.x*256 + threadIdx.x;
  int v = (i < Nn) ? deg[i] : 0;
  #pragma unroll
  for (int off=1; off<64; off<<=1) v += __shfl_xor(v, off);
  __shared__ int ws[4];
  if ((threadIdx.x & 63) == 0) ws[threadIdx.x >> 6] = v;
  __syncthreads();
  if (threadIdx.x == 0) bsum[blockIdx.x] = ws[0] + ws[1] + ws[2] + ws[3];
}

// stage 2: single-block exclusive scan of bsum[NB] in place; also writes rowptr[Nn]=E
__global__ __launch_bounds__(1024) void scan_p2(int* __restrict__ bsum, int NB, int E,
                                                int* __restrict__ rowptr, int Nn){
  __shared__ int wsum[16];
  __shared__ int carry_s;
  if (threadIdx.x == 0) carry_s = 0;
  __syncthreads();
  const int lane = threadIdx.x & 63, w = threadIdx.x >> 6;
  for (int base = 0; base < NB; base += 1024){
    int i = base + threadIdx.x;
    int v = (i < NB) ? bsum[i] : 0;
    int s = v;
    #pragma unroll
    for (int off=1; off<64; off<<=1){ int t = __shfl_up(s, off); if (lane >= off) s += t; }
    if (lane == 63) wsum[w] = s;
    __syncthreads();
    if (threadIdx.x < 16){
      int ws = wsum[threadIdx.x];
      #pragma unroll
      for (int off=1; off<16; off<<=1){ int t = __shfl_up(ws, off); if (threadIdx.x >= off) ws += t; }
      wsum[threadIdx.x] = ws;   // inclusive scan of wave totals
    }
    __syncthreads();
    int carry = carry_s;
    int excl = carry + (w ? wsum[w-1] : 0) + (s - v);
    if (i < NB) bsum[i] = excl;
    __syncthreads();
    if (threadIdx.x == 1023) carry_s = carry + wsum[15];
    __syncthreads();
  }
  if (threadIdx.x == 0) rowptr[Nn] = E;
}

// stage 3: per-block exclusive scan of deg tile + block offset -> rowptr, cursor
__global__ __launch_bounds__(256) void scan_p3(const int* __restrict__ deg,
      const int* __restrict__ boff, int Nn,
      int* __restrict__ rowptr, int* __restrict__ cursor){
  int i = blockIdx.x*256 + threadIdx.x;
  int v = (i < Nn) ? deg[i] : 0;
  const int lane = threadIdx.x & 63, w = threadIdx.x >> 6;
  int s = v;
  #pragma unroll
  for (int off=1; off<64; off<<=1){ int t = __shfl_up(s, off); if (lane >= off) s += t; }
  __shared__ int wsum[4];
  if (lane == 63) wsum[w] = s;
  __syncthreads();
  int wpre = 0;
  #pragma unroll
  for (int k=0;k<4;k++) if (k < w) wpre += wsum[k];
  int excl = boff[blockIdx.x] + wpre + (s - v);
  if (i < Nn){ rowptr[i] = excl; cursor[i] = excl; }
}

__global__ void edge_scatter(const int* __restrict__ ei, const int* __restrict__ ety, int E,
                             int* __restrict__ cursor, unsigned* __restrict__ srcet){
  int e = blockIdx.x*blockDim.x + threadIdx.x;
  if (e >= E) return;
  int pos = atomicAdd(&cursor[ei[E + e]], 1);
  srcet[pos] = ((unsigned)ety[e] << 16) | (unsigned)ei[e];
}

// ---------------- QKV GEMM (MFMA): Q f16 [N,128]; KV packed [N,64] lanes of [k0,k1,v0,v1] f16 ----------------
__global__ __launch_bounds__(256) void gemm_qkv(const bf16* __restrict__ nfb, const bf16* __restrict__ qeb,
      const bf16* __restrict__ Wcat, const float* __restrict__ bcat,
      short* __restrict__ Qs, short* __restrict__ KVs, int M){
  constexpr int BK=32, LDT=40, K=256;
  __shared__ short As[64*LDT];
  __shared__ short Bs[64*LDT];
  const int tid  = threadIdx.x;
  const int lane = tid & 63;
  const int wave = tid >> 6;
  const int wm = (wave >> 1) * 32, wn = (wave & 1) * 32;
  const long m0 = (long)blockIdx.x * 64;
  const int  n0 = blockIdx.y * 64;
  floatx4 acc00 = {0.f,0.f,0.f,0.f}, acc01 = {0.f,0.f,0.f,0.f};
  floatx4 acc10 = {0.f,0.f,0.f,0.f}, acc11 = {0.f,0.f,0.f,0.f};
  const int srow = tid >> 2, scg = (tid & 3) * 8;
  const int r = lane & 15, q = lane >> 4;
  const short* Ag = (const short*)nfb;
  const short* Qg = (const short*)qeb;
  const short* Bg = (const short*)Wcat;
  for (int k0 = 0; k0 < K; k0 += BK){
    short8 va = {0,0,0,0,0,0,0,0};
    if (k0 < 128){
      long ar = m0 + srow;
      if (ar < M) va = *(const short8*)(Ag + ar*128 + k0 + scg);
    } else {
      va = *(const short8*)(Qg + (k0-128) + scg);   // row-independent broadcast
    }
    *(short8*)(&As[srow*LDT + scg]) = va;
    *(short8*)(&Bs[srow*LDT + scg]) = *(const short8*)(Bg + (long)(n0 + srow)*K + k0 + scg);
    __syncthreads();
    short8 a0 = *(const short8*)(&As[(wm      + r)*LDT + q*8]);
    short8 a1 = *(const short8*)(&As[(wm + 16 + r)*LDT + q*8]);
    short8 b0 = *(const short8*)(&Bs[(wn      + r)*LDT + q*8]);
    short8 b1 = *(const short8*)(&Bs[(wn + 16 + r)*LDT + q*8]);
    acc00 = __builtin_amdgcn_mfma_f32_16x16x32_bf16(a0, b0, acc00, 0, 0, 0);
    acc01 = __builtin_amdgcn_mfma_f32_16x16x32_bf16(a0, b1, acc01, 0, 0, 0);
    acc10 = __builtin_amdgcn_mfma_f32_16x16x32_bf16(a1, b0, acc10, 0, 0, 0);
    acc11 = __builtin_amdgcn_mfma_f32_16x16x32_bf16(a1, b1, acc11, 0, 0, 0);
    __syncthreads();
  }
  #pragma unroll
  for (int i=0;i<2;i++)
  #pragma unroll
  for (int j=0;j<2;j++){
    floatx4 av = (i==0) ? ((j==0)?acc00:acc01) : ((j==0)?acc10:acc11);
    int col = n0 + wn + j*16 + r;
    float bsv = bcat[col];
    #pragma unroll
    for (int g=0; g<4; g++){
      long row = m0 + wm + i*16 + q*4 + g;
      if (row < M){
        short bits = hfbits(av[g] + bsv);
        if (col < 128)      Qs[row*128 + col] = bits;
        else if (col < 256){ int d = col - 128; KVs[row*256 + ((d>>1)<<2) + (d&1)] = bits; }
        else               { int d = col - 256; KVs[row*256 + ((d>>1)<<2) + 2 + (d&1)] = bits; }
      }
    }
  }
}

// ---------------- generic GEMM (MFMA, used for Wo): C f32 = A_bf16 @ B_bf16^T + bias ----------------
__global__ __launch_bounds__(256) void gemm_bt(const bf16* __restrict__ A, const bf16* __restrict__ B,
      const float* __restrict__ bias, float* __restrict__ C, int M, int N, int K){
  constexpr int BK=32, LDT=40;
  __shared__ short As[64*LDT];
  __shared__ short Bs[64*LDT];
  const int tid  = threadIdx.x;
  const int lane = tid & 63;
  const int wave = tid >> 6;
  const int wm = (wave >> 1) * 32, wn = (wave & 1) * 32;
  const long m0 = (long)blockIdx.x * 64;
  const int  n0 = blockIdx.y * 64;
  floatx4 acc00 = {0.f,0.f,0.f,0.f}, acc01 = {0.f,0.f,0.f,0.f};
  floatx4 acc10 = {0.f,0.f,0.f,0.f}, acc11 = {0.f,0.f,0.f,0.f};
  const int srow = tid >> 2, scg = (tid & 3) * 8;
  const int r = lane & 15, q = lane >> 4;
  const short* Ag = (const short*)A;
  const short* Bg = (const short*)B;
  for (int k0 = 0; k0 < K; k0 += BK){
    short8 va = {0,0,0,0,0,0,0,0};
    long ar = m0 + srow;
    if (ar < M) va = *(const short8*)(Ag + ar*K + k0 + scg);
    *(short8*)(&As[srow*LDT + scg]) = va;
    *(short8*)(&Bs[srow*LDT + scg]) = *(const short8*)(Bg + (long)(n0 + srow)*K + k0 + scg);
    __syncthreads();
    short8 a0 = *(const short8*)(&As[(wm      + r)*LDT + q*8]);
    short8 a1 = *(const short8*)(&As[(wm + 16 + r)*LDT + q*8]);
    short8 b0 = *(const short8*)(&Bs[(wn      + r)*LDT + q*8]);
    short8 b1 = *(const short8*)(&Bs[(wn + 16 + r)*LDT + q*8]);
    acc00 = __builtin_amdgcn_mfma_f32_16x16x32_bf16(a0, b0, acc00, 0, 0, 0);
    acc01 = __builtin_amdgcn_mfma_f32_16x16x32_bf16(a0, b1, acc01, 0, 0, 0);
    acc10 = __builtin_amdgcn_mfma_f32_16x16x32_bf16(a1, b0, acc10, 0, 0, 0);
    acc11 = __builtin_amdgcn_mfma_f32_16x16x32_bf16(a1, b1, acc11, 0, 0, 0);
    __syncthreads();
  }
  #pragma unroll
  for (int i=0;i<2;i++)
  #pragma unroll
  for (int j=0;j<2;j++){
    floatx4 av = (i==0) ? ((j==0)?acc00:acc01) : ((j==0)?acc10:acc11);
    int col = n0 + wn + j*16 + r;
    float bsv = bias[col];
    #pragma unroll
    for (int g=0; g<4; g++){
      long row = m0 + wm + i*16 + q*4 + g;
      if (row < M) C[row*(long)N + col] = av[g] + bsv;
    }
  }
}

// ---------------- attention: 1 wave per node, lane owns dims {2l,2l+1} as f16 pairs ----------------
// Edge loop unrolled x4: 4 independent KV-gather + score chains in flight per wave
// to cover L2-miss/L3 latency (counters showed VALUBusy 43%, HBM 32% -> latency-bound).
__global__ __launch_bounds__(256) void attn_agg(const unsigned* __restrict__ Qh,
     const uint2* __restrict__ KVh, const unsigned* __restrict__ Rh,
     const int* __restrict__ rowptr, const unsigned* __restrict__ srcet,
     unsigned* __restrict__ agg, int Nn){
  const int w = threadIdx.x >> 6, l = threadIdx.x & 63;
  const int n = blockIdx.x*4 + w;
  if (n >= Nn) return;
  hf2 q2 = u2h2(Qh[(long)n*64 + l]);
  int beg = rowptr[n], end = rowptr[n+1];
  float acc0 = 0.f, acc1 = 0.f, denom = 0.f;
  for (int c = beg; c < end; c += 64){
    int cnt = end - c; if (cnt > 64) cnt = 64;
    unsigned se_l = (c + l < end) ? srcet[c + l] : 0u;
    int j = 0;
    for (; j + 4 <= cnt; j += 4){
      unsigned se0 = __shfl(se_l, j+0);
      unsigned se1 = __shfl(se_l, j+1);
      unsigned se2 = __shfl(se_l, j+2);
      unsigned se3 = __shfl(se_l, j+3);
      uint2 kv0 = KVh[(long)(se0 & 0xFFFF)*64 + l];
      uint2 kv1 = KVh[(long)(se1 & 0xFFFF)*64 + l];
      uint2 kv2 = KVh[(long)(se2 & 0xFFFF)*64 + l];
      uint2 kv3 = KVh[(long)(se3 & 0xFFFF)*64 + l];
      unsigned r0 = Rh[(se0 >> 16)*64 + l];
      unsigned r1 = Rh[(se1 >> 16)*64 + l];
      unsigned r2 = Rh[(se2 >> 16)*64 + l];
      unsigned r3 = Rh[(se3 >> 16)*64 + l];
      hf2 kb0 = u2h2(kv0.x) + u2h2(r0);
      hf2 kb1 = u2h2(kv1.x) + u2h2(r1);
      hf2 kb2 = u2h2(kv2.x) + u2h2(r2);
      hf2 kb3 = u2h2(kv3.x) + u2h2(r3);
#if __has_builtin(__builtin_amdgcn_fdot2)
      float p0 = __builtin_amdgcn_fdot2(q2, kb0, 0.f, false);
      float p1 = __builtin_amdgcn_fdot2(q2, kb1, 0.f, false);
      float p2 = __builtin_amdgcn_fdot2(q2, kb2, 0.f, false);
      float p3 = __builtin_amdgcn_fdot2(q2, kb3, 0.f, false);
#else
      float p0 = fmaf((float)q2.y, (float)kb0.y, (float)q2.x * (float)kb0.x);
      float p1 = fmaf((float)q2.y, (float)kb1.y, (float)q2.x * (float)kb1.x);
      float p2 = fmaf((float)q2.y, (float)kb2.y, (float)q2.x * (float)kb2.x);
      float p3 = fmaf((float)q2.y, (float)kb3.y, (float)q2.x * (float)kb3.x);
#endif
      p0 += __shfl_xor(p0, 1); p1 += __shfl_xor(p1, 1);
      p2 += __shfl_xor(p2, 1); p3 += __shfl_xor(p3, 1);
      p0 += __shfl_xor(p0, 2); p1 += __shfl_xor(p1, 2);
      p2 += __shfl_xor(p2, 2); p3 += __shfl_xor(p3, 2);
      p0 += __shfl_xor(p0, 4); p1 += __shfl_xor(p1, 4);
      p2 += __shfl_xor(p2, 4); p3 += __shfl_xor(p3, 4);
      float e0 = __expf(p0 * 0.25f);
      float e1 = __expf(p1 * 0.25f);
      float e2 = __expf(p2 * 0.25f);
      float e3 = __expf(p3 * 0.25f);
      denom += e0; denom += e1; denom += e2; denom += e3;
      hf2 v0 = u2h2(kv0.y), v1 = u2h2(kv1.y), v2 = u2h2(kv2.y), v3 = u2h2(kv3.y);
      acc0 = fmaf(e0, (float)v0.x, acc0);
      acc1 = fmaf(e0, (float)v0.y, acc1);
      acc0 = fmaf(e1, (float)v1.x, acc0);
      acc1 = fmaf(e1, (float)v1.y, acc1);
      acc0 = fmaf(e2, (float)v2.x, acc0);
      acc1 = fmaf(e2, (float)v2.y, acc1);
      acc0 = fmaf(e3, (float)v3.x, acc0);
      acc1 = fmaf(e3, (float)v3.y, acc1);
    }
    for (; j < cnt; ++j){
      unsigned se = __shfl(se_l, j);
      int src = se & 0xFFFF;
      int et  = se >> 16;
      uint2 kv = KVh[(long)src*64 + l];
      hf2 kb = u2h2(kv.x) + u2h2(Rh[et*64 + l]);
#if __has_builtin(__builtin_amdgcn_fdot2)
      float p = __builtin_amdgcn_fdot2(q2, kb, 0.f, false);
#else
      float p = fmaf((float)q2.y, (float)kb.y, (float)q2.x * (float)kb.x);
#endif
      p += __shfl_xor(p, 1); p += __shfl_xor(p, 2); p += __shfl_xor(p, 4);
      float es = __expf(p * 0.25f);
      denom += es;
      hf2 v2 = u2h2(kv.y);
      acc0 = fmaf(es, (float)v2.x, acc0);
      acc1 = fmaf(es, (float)v2.y, acc1);
    }
  }
  float inv = 1.f / (denom + 1e-8f);
  unsigned out = ((unsigned)(unsigned short)bfbits(acc1 * inv) << 16)
               |  (unsigned)(unsigned short)bfbits(acc0 * inv);
  agg[(long)n*64 + l] = out;
}

// ---------------- residual + LN1: x = LN(nf + attn), out bf16 ----------------
__global__ __launch_bounds__(128) void ln_add1(const float* __restrict__ nf, const float* __restrict__ attn,
     const float* __restrict__ g, const float* __restrict__ b, bf16* __restrict__ xout){
  long n = blockIdx.x; int t = threadIdx.x;
  float y = nf[n*128 + t] + attn[n*128 + t];
  float s = y, s2 = y*y;
  #pragma unroll
  for (int off=32; off>0; off>>=1){ s += __shfl_xor(s, off); s2 += __shfl_xor(s2, off); }
  __shared__ float ps[4];
  if ((t & 63) == 0){ ps[(t>>6)*2] = s; ps[(t>>6)*2+1] = s2; }
  __syncthreads();
  float tot = ps[0] + ps[2], tot2 = ps[1] + ps[3];
  float mu = tot * (1.f/128.f);
  float var = tot2 * (1.f/128.f) - mu*mu;
  float rs = rsqrtf(var + 1e-5f);
  xout[n*128 + t] = f2b((y - mu)*rs*g[t] + b[t]);
}

// ---------------- fused FFN (MFMA), weights consumed DIRECTLY from global (L2-resident) ----------------
// All 782 blocks read the same W1/W2 -> L2 serves them; B-fragments of mfma_16x16x32 are
// plain strided 16B/lane global loads, so LDS staging of weights was pure overhead:
// it cost 24 extra barriers/block + ds_writes and capped occupancy. Now LDS = Xs+Hs only
// (34.5 KB -> 4 blocks/CU) and 9 barriers/block (Hs produce->consume handoffs only).
__global__ __launch_bounds__(256) void ffn_fused(const bf16* __restrict__ X, const bf16* __restrict__ W1,
    const float* __restrict__ b1, const bf16* __restrict__ W2, const float* __restrict__ b2,
    float* __restrict__ Out, int M){
  __shared__ short Xs[64*136];
  __shared__ short Hs[64*140];
  const int tid = threadIdx.x, lane = tid & 63, wave = tid >> 6;
  const int r = lane & 15, q = lane >> 4;
  const int wm = (wave >> 1) * 32, wn = (wave & 1) * 32;
  const long m0 = (long)blockIdx.x * 64;
  const short* Xg  = (const short*)X;
  const short* W1g = (const short*)W1;
  const short* W2g = (const short*)W2;
  #pragma unroll
  for (int c=0;c<4;c++){
    int idx = c*256 + tid, row = idx >> 4, ch = (idx & 15) * 8;
    short8 v = {0,0,0,0,0,0,0,0};
    long ar = m0 + row;
    if (ar < M) v = *(const short8*)(Xg + ar*128 + ch);
    *(short8*)(&Xs[row*136 + ch]) = v;
  }
  __syncthreads();
  const int wn2 = (wave & 1) * 64;
  floatx4 o[2][4];
  #pragma unroll
  for (int i=0;i<2;i++)
  #pragma unroll
  for (int j=0;j<4;j++) o[i][j] = (floatx4){0.f,0.f,0.f,0.f};
  for (int qtr = 0; qtr < 4; ++qtr){
    const int hb = qtr * 128;
    // ---- GEMM1: H[:, hb:hb+128] = gelu(X @ W1[hb:hb+128,:]^T + b1), B direct from global
    #pragma unroll
    for (int c0 = 0; c0 < 128; c0 += 64){
      floatx4 h00 = {0.f,0.f,0.f,0.f}, h01 = {0.f,0.f,0.f,0.f};
      floatx4 h10 = {0.f,0.f,0.f,0.f}, h11 = {0.f,0.f,0.f,0.f};
      #pragma unroll
      for (int k0 = 0; k0 < 128; k0 += 32){
        short8 b0 = *(const short8*)(W1g + (long)(hb + c0 + wn      + r)*128 + k0 + q*8);
        short8 bv = *(const short8*)(W1g + (long)(hb + c0 + wn + 16 + r)*128 + k0 + q*8);
        short8 a0 = *(const short8*)(&Xs[(wm      + r)*136 + k0 + q*8]);
        short8 a1 = *(const short8*)(&Xs[(wm + 16 + r)*136 + k0 + q*8]);
        h00 = __builtin_amdgcn_mfma_f32_16x16x32_bf16(a0, b0, h00, 0, 0, 0);
        h01 = __builtin_amdgcn_mfma_f32_16x16x32_bf16(a0, bv, h01, 0, 0, 0);
        h10 = __builtin_amdgcn_mfma_f32_16x16x32_bf16(a1, b0, h10, 0, 0, 0);
        h11 = __builtin_amdgcn_mfma_f32_16x16x32_bf16(a1, bv, h11, 0, 0, 0);
      }
      #pragma unroll
      for (int i=0;i<2;i++)
      #pragma unroll
      for (int j=0;j<2;j++){
        floatx4 av = (i==0) ? ((j==0)?h00:h01) : ((j==0)?h10:h11);
        int col = wn + j*16 + r;
        float bb = b1[hb + c0 + col];
        #pragma unroll
        for (int g=0; g<4; g++){
          int row = wm + i*16 + q*4 + g;
          float v = av[g] + bb;
          v = 0.5f * v * (1.f + erff(v * 0.70710678118f));   // exact GELU
          Hs[row*140 + c0 + col] = bfbits(v);
        }
      }
    }
    __syncthreads();   // Hs complete for this quarter
    // ---- GEMM2 partial: o += H_qtr @ W2[:, hb:hb+128]^T, B direct from global
    #pragma unroll
    for (int k0 = 0; k0 < 128; k0 += 32){
      short8 a0 = *(const short8*)(&Hs[(wm      + r)*140 + k0 + q*8]);
      short8 a1 = *(const short8*)(&Hs[(wm + 16 + r)*140 + k0 + q*8]);
      #pragma unroll
      for (int j=0;j<4;j++){
        short8 bj = *(const short8*)(W2g + (long)(wn2 + j*16 + r)*512 + hb + k0 + q*8);
        o[0][j] = __builtin_amdgcn_mfma_f32_16x16x32_bf16(a0, bj, o[0][j], 0, 0, 0);
        o[1][j] = __builtin_amdgcn_mfma_f32_16x16x32_bf16(a1, bj, o[1][j], 0, 0, 0);
      }
    }
    __syncthreads();   // before next quarter overwrites Hs
  }
  #pragma unroll
  for (int i=0;i<2;i++)
  #pragma unroll
  for (int j=0;j<4;j++){
    int col = wn2 + j*16 + r;
    float bb = b2[col];
    #pragma unroll
    for (int g=0; g<4; g++){
      long row = m0 + wm + i*16 + q*4 + g;
      if (row < M) Out[row*128 + col] = o[i][j][g] + bb;
    }
  }
}

// ---------------- residual + LN2: out = LN(x + ffo), f32 out ----------------
__global__ __launch_bounds__(128) void ln_add2(const bf16* __restrict__ X, const float* __restrict__ ffo,
     const float* __restrict__ g, const float* __restrict__ b, float* __restrict__ out){
  long n = blockIdx.x; int t = threadIdx.x;
  float y = b2f(X[n*128 + t]) + ffo[n*128 + t];
  float s = y, s2 = y*y;
  #pragma unroll
  for (int off=32; off>0; off>>=1){ s += __shfl_xor(s, off); s2 += __shfl_xor(s2, off); }
  __shared__ float ps[4];
  if ((t & 63) == 0){ ps[(t>>6)*2] = s; ps[(t>>6)*2+1] = s2; }
  __syncthreads();
  float tot = ps[0] + ps[2], tot2 = ps[1] + ps[3];
  float mu = tot * (1.f/128.f);
  float var = tot2 * (1.f/128.f) - mu*mu;
  float rs = rsqrtf(var + 1e-5f);
  out[n*128 + t] = (y - mu)*rs*g[t] + b[t];
}

// ---------------- relational interaction layer (R=100, naive f32) ----------------
__device__ __forceinline__ float dotf(const float* __restrict__ s, const float* __restrict__ w, int n){
  float acc = 0.f;
  const float4* w4 = (const float4*)w;
  #pragma unroll 4
  for (int j = 0; j < (n >> 2); ++j){
    float4 wv = w4[j];
    acc += s[4*j]*wv.x + s[4*j+1]*wv.y + s[4*j+2]*wv.z + s[4*j+3]*wv.w;
  }
  return acc;
}

__global__ __launch_bounds__(128) void rel_layer(const float* __restrict__ rel, const float* __restrict__ relW,
    const float* __restrict__ relb, const float* __restrict__ Wc, const float* __restrict__ bc,
    const float* __restrict__ gn, const float* __restrict__ bn, float* __restrict__ out){
  int rr = blockIdx.x, t = threadIdx.x;
  __shared__ float rrow[128];
  __shared__ float comb[512];
  rrow[t] = rel[(long)rr*128 + t];
  __syncthreads();
  #pragma unroll
  for (int k=0;k<4;k++){
    comb[k*128 + t] = dotf(rrow, relW + ((long)(k*128) + t)*128, 128) + relb[k*128 + t];
  }
  __syncthreads();
  float c2 = dotf(comb, Wc + (long)t*512, 512) + bc[t];
  float y = rrow[t] + c2;
  float s = y, s2 = y*y;
  #pragma unroll
  for (int off=32; off>0; off>>=1){ s += __shfl_xor(s, off); s2 += __shfl_xor(s2, off); }
  __shared__ float ps[4];
  if ((t & 63) == 0){ ps[(t>>6)*2] = s; ps[(t>>6)*2+1] = s2; }
  __syncthreads();
  float tot = ps[0] + ps[2], tot2 = ps[1] + ps[3];
  float mu = tot * (1.f/128.f);
  float var = tot2 * (1.f/128.f) - mu*mu;
  float rs = rsqrtf(var + 1e-5f);
  out[(long)rr*128 + t] = (y - mu)*rs*gn[t] + bn[t];
}

extern "C" void kernel_launch(void* const* d_in, const int* in_sizes, int n_in,
                              void* d_out, int out_size, void* d_ws, size_t ws_size,
                              hipStream_t stream){
  const int H = 128;
  auto S = [&](int i){ return in_sizes[i]; };
  bool ok = (n_in == 27);
  if (ok){
    ok = ok && S(1)==H && (S(0)%H)==0 && S(2)==2*S(3) && (S(4)%H)==0;
    ok = ok && S(5)==2*H*H && S(7)==2*H*H && S(9)==H*H && S(11)==H*H;
    ok = ok && S(17)==4*H*H && S(19)==4*H*H && S(21)==4*H*H && S(23)==4*H*H;
    ok = ok && out_size == S(0) + S(4);
  }
  if (!ok){
    fill_const<<<(out_size + 255)/256, 256, 0, stream>>>((float*)d_out, 100.0f, out_size);
    return;
  }

  const float* nf   = (const float*)d_in[0];
  const float* qe   = (const float*)d_in[1];
  const int*   ei   = (const int*)  d_in[2];
  const int*   ety  = (const int*)  d_in[3];
  const float* rel  = (const float*)d_in[4];
  const float* Wq   = (const float*)d_in[5];
  const float* bq   = (const float*)d_in[6];
  const float* Wk   = (const float*)d_in[7];
  const float* bk   = (const float*)d_in[8];
  const float* Wv   = (const float*)d_in[9];
  const float* bv   = (const float*)d_in[10];
  const float* Wo   = (const float*)d_in[11];
  const float* bo   = (const float*)d_in[12];
  const float* n1g  = (const float*)d_in[13];
  const float* n1b  = (const float*)d_in[14];
  const float* n2g  = (const float*)d_in[15];
  const float* n2b  = (const float*)d_in[16];
  const float* W1   = (const float*)d_in[17];
  const float* b1   = (const float*)d_in[18];
  const float* W2   = (const float*)d_in[19];
  const float* b2v  = (const float*)d_in[20];
  const float* relW = (const float*)d_in[21];
  const float* relbp= (const float*)d_in[22];
  const float* Wc   = (const float*)d_in[23];
  const float* bc   = (const float*)d_in[24];
  const float* rng  = (const float*)d_in[25];
  const float* rnb  = (const float*)d_in[26];

  const int N = in_sizes[0] / 128;
  const int E = in_sizes[2] / 2;
  const int R = in_sizes[4] / 128;

  char* ws = (char*)d_ws;
  size_t off = 0;
  auto alloc = [&](size_t bytes)->char*{
    char* p = ws + off; off = (off + bytes + 255) & ~(size_t)255; return p;
  };
  // regNA: nfb bf16 [N,128] -> aggp bf16 [N,128] (nfb dead after gemm_qkv)
  char*     regNA  = alloc((size_t)N * 256);
  // regKV: KVh uint2 [N,64] -> attn f32 [N,128] -> ffo f32 [N,128]
  char*     regKV  = alloc((size_t)N * 512);
  unsigned* Qh     = (unsigned*)alloc((size_t)N * 256);   // f16 pairs; dead after attn_agg
  bf16*     xlb    = (bf16*)    alloc((size_t)N * 256);
  bf16*     qeb    = (bf16*)    alloc(256);
  bf16*     Wcat   = (bf16*)    alloc((size_t)384*256*2);
  float*    bcat   = (float*)   alloc(384*4);
  bf16*     Wob    = (bf16*)    alloc((size_t)128*128*2);
  bf16*     W1b    = (bf16*)    alloc((size_t)512*128*2);
  bf16*     W2b    = (bf16*)    alloc((size_t)128*512*2);
  short*    Rh     = (short*)   alloc((size_t)R*128*2);   // rel embeddings f16
  int*      deg    = (int*)     alloc((size_t)N * 4);
  int*      rowptr = (int*)     alloc((size_t)(N+1) * 4);
  int*      cursor = (int*)     alloc((size_t)N * 4);
  unsigned* srcet  = (unsigned*)alloc((size_t)E * 4);
  const int NB = (N + 255) / 256;
  int*      bsum   = (int*)     alloc((size_t)NB * 4);

  if (off > ws_size){
    fill_const<<<(out_size + 255)/256, 256, 0, stream>>>((float*)d_out, 50.0f, out_size);
    return;
  }

  bf16*     nfb  = (bf16*)regNA;
  unsigned* aggp = (unsigned*)regNA;  // bf16 pairs, overlays nfb
  uint2*    KVh  = (uint2*)regKV;
  float*    attn = (float*)regKV;     // overlays KVh (dead after attn_agg)
  float*    ffo  = (float*)regKV;     // overlays attn (dead after ln_add1)
  float*    outx = (float*)d_out;
  float*    outr = (float*)d_out + (size_t)N*128;

  // conversions
  conv_f2b<<<(N*128 + 255)/256, 256, 0, stream>>>(nf, nfb, N*128);
  conv_f2b<<<1, 128, 0, stream>>>(qe, qeb, 128);
  build_wcat<<<(384*256 + 255)/256, 256, 0, stream>>>(Wq, Wk, Wv, bq, bk, bv, Wcat, bcat);
  conv_f2b<<<(128*128 + 255)/256, 256, 0, stream>>>(Wo, Wob, 128*128);
  conv_f2b<<<(512*128 + 255)/256, 256, 0, stream>>>(W1, W1b, 512*128);
  conv_f2b<<<(128*512 + 255)/256, 256, 0, stream>>>(W2, W2b, 128*512);
  conv_f2h<<<(R*128 + 255)/256, 256, 0, stream>>>(rel, Rh, R*128);

  // CSR (hierarchical scan: per-block reduce -> scan block sums -> per-block scan)
  hipMemsetAsync(deg, 0, (size_t)N*4, stream);
  edge_hist<<<(E + 255)/256, 256, 0, stream>>>(ei, E, deg);
  scan_p1<<<NB, 256, 0, stream>>>(deg, N, bsum);
  scan_p2<<<1, 1024, 0, stream>>>(bsum, NB, E, rowptr, N);
  scan_p3<<<NB, 256, 0, stream>>>(deg, bsum, N, rowptr, cursor);
  edge_scatter<<<(E + 255)/256, 256, 0, stream>>>(ei, ety, E, cursor, srcet);

  // pipeline
  dim3 g1((N + 63)/64, 6);
  gemm_qkv<<<g1, 256, 0, stream>>>(nfb, qeb, Wcat, bcat, (short*)Qh, (short*)KVh, N);
  attn_agg<<<(N + 3)/4, 256, 0, stream>>>(Qh, KVh, (const unsigned*)Rh, rowptr, srcet, aggp, N);
  dim3 g2((N + 63)/64, 2);
  gemm_bt<<<g2, 256, 0, stream>>>((const bf16*)aggp, Wob, bo, attn, N, 128, 128);
  ln_add1<<<N, 128, 0, stream>>>(nf, attn, n1g, n1b, xlb);
  ffn_fused<<<(N + 63)/64, 256, 0, stream>>>(xlb, W1b, b1, W2b, b2v, ffo, N);
  ln_add2<<<N, 128, 0, stream>>>(xlb, ffo, n2g, n2b, outx);
  rel_layer<<<R, 128, 0, stream>>>(rel, relW, relbp, Wc, bc, rng, rnb, outr);
}

// Round 5
// 443.445 us; speedup vs baseline: 1.0937x; 1.0937x over previous
//
#include <hip/hip_runtime.h>
#include <hip/hip_bf16.h>
#include <math.h>

using bf16 = __hip_bfloat16;
typedef _Float16 hf;
typedef hf __attribute__((ext_vector_type(2))) hf2;
typedef __attribute__((ext_vector_type(8))) short short8;
typedef __attribute__((ext_vector_type(4))) float floatx4;

__device__ __forceinline__ float b2f(bf16 x){ return __bfloat162float(x); }
__device__ __forceinline__ bf16 f2b(float x){ return __float2bfloat16(x); }
__device__ __forceinline__ short bfbits(float x){ bf16 t = __float2bfloat16(x); return *(short*)&t; }
__device__ __forceinline__ short hfbits(float x){ hf t = (hf)x; return *(short*)&t; }
__device__ __forceinline__ hf2 u2h2(unsigned u){ return *(hf2*)&u; }

__global__ void fill_const(float* __restrict__ p, float v, int n){
  int i = blockIdx.x*blockDim.x + threadIdx.x;
  if (i < n) p[i] = v;
}

__global__ void conv_f2b(const float* __restrict__ src, bf16* __restrict__ dst, int n){
  int i = blockIdx.x*blockDim.x + threadIdx.x;
  if (i < n) dst[i] = f2b(src[i]);
}

__global__ void conv_f2h(const float* __restrict__ src, short* __restrict__ dst, int n){
  int i = blockIdx.x*blockDim.x + threadIdx.x;
  if (i < n) dst[i] = hfbits(src[i]);
}

// Wcat bf16 [384,256] = [Wq; Wk; Wv|0], bcat f32 [384]
__global__ void build_wcat(const float* __restrict__ Wq, const float* __restrict__ Wk,
                           const float* __restrict__ Wv, const float* __restrict__ bq,
                           const float* __restrict__ bk, const float* __restrict__ bv,
                           bf16* __restrict__ Wcat, float* __restrict__ bcat){
  int i = blockIdx.x*blockDim.x + threadIdx.x;
  if (i >= 384*256) return;
  int r = i >> 8, c = i & 255;
  float v;
  if (r < 128)       v = Wq[r*256 + c];
  else if (r < 256)  v = Wk[(r-128)*256 + c];
  else               v = (c < 128) ? Wv[(r-256)*128 + c] : 0.f;
  Wcat[i] = f2b(v);
  if (i < 384) bcat[i] = (i < 128) ? bq[i] : (i < 256 ? bk[i-128] : bv[i-256]);
}

// ---------------- CSR build ----------------
__global__ void edge_hist(const int* __restrict__ ei, int E, int* __restrict__ deg){
  int e = blockIdx.x*blockDim.x + threadIdx.x;
  if (e >= E) return;
  atomicAdd(&deg[ei[E + e]], 1);
}

// Hierarchical scan, stage 1: per-block (256-elem) reduce of deg -> bsum[block]
__global__ __launch_bounds__(256) void scan_p1(const int* __restrict__ deg, int Nn,
                                               int* __restrict__ bsum){
  int i = blockIdx.x*256 + threadIdx.x;
  int v = (i < Nn) ? deg[i] : 0;
  #pragma unroll
  for (int off=1; off<64; off<<=1) v += __shfl_xor(v, off);
  __shared__ int ws[4];
  if ((threadIdx.x & 63) == 0) ws[threadIdx.x >> 6] = v;
  __syncthreads();
  if (threadIdx.x == 0) bsum[blockIdx.x] = ws[0] + ws[1] + ws[2] + ws[3];
}

// stage 2: single-block exclusive scan of bsum[NB] in place; also writes rowptr[Nn]=E
__global__ __launch_bounds__(1024) void scan_p2(int* __restrict__ bsum, int NB, int E,
                                                int* __restrict__ rowptr, int Nn){
  __shared__ int wsum[16];
  __shared__ int carry_s;
  if (threadIdx.x == 0) carry_s = 0;
  __syncthreads();
  const int lane = threadIdx.x & 63, w = threadIdx.x >> 6;
  for (int base = 0; base < NB; base += 1024){
    int i = base + threadIdx.x;
    int v = (i < NB) ? bsum[i] : 0;
    int s = v;
    #pragma unroll
    for (int off=1; off<64; off<<=1){ int t = __shfl_up(s, off); if (lane >= off) s += t; }
    if (lane == 63) wsum[w] = s;
    __syncthreads();
    if (threadIdx.x < 16){
      int ws = wsum[threadIdx.x];
      #pragma unroll
      for (int off=1; off<16; off<<=1){ int t = __shfl_up(ws, off); if (threadIdx.x >= off) ws += t; }
      wsum[threadIdx.x] = ws;   // inclusive scan of wave totals
    }
    __syncthreads();
    int carry = carry_s;
    int excl = carry + (w ? wsum[w-1] : 0) + (s - v);
    if (i < NB) bsum[i] = excl;
    __syncthreads();
    if (threadIdx.x == 1023) carry_s = carry + wsum[15];
    __syncthreads();
  }
  if (threadIdx.x == 0) rowptr[Nn] = E;
}

// stage 3: per-block exclusive scan of deg tile + block offset -> rowptr, cursor
__global__ __launch_bounds__(256) void scan_p3(const int* __restrict__ deg,
      const int* __restrict__ boff, int Nn,
      int* __restrict__ rowptr, int* __restrict__ cursor){
  int i = blockIdx.x*256 + threadIdx.x;
  int v = (i < Nn) ? deg[i] : 0;
  const int lane = threadIdx.x & 63, w = threadIdx.x >> 6;
  int s = v;
  #pragma unroll
  for (int off=1; off<64; off<<=1){ int t = __shfl_up(s, off); if (lane >= off) s += t; }
  __shared__ int wsum[4];
  if (lane == 63) wsum[w] = s;
  __syncthreads();
  int wpre = 0;
  #pragma unroll
  for (int k=0;k<4;k++) if (k < w) wpre += wsum[k];
  int excl = boff[blockIdx.x] + wpre + (s - v);
  if (i < Nn){ rowptr[i] = excl; cursor[i] = excl; }
}

// dst-partitioned scatter: 8 node-ranges; pass = bid&7 aligns with round-robin
// block->XCD dispatch so each XCD's L2 owns one ~E/8*4B srcet region. Writes to a
// cache line then accumulate within one L2 before writeback -> kills the 53MB
// write amplification (was: 800k random 4B stores = full-line writebacks each).
// Edge arrays (6.4MB) are re-read 8x but L2/L3-resident after pass 0.
// Correctness does NOT depend on the XCD mapping (G16) - only locality does.
__global__ __launch_bounds__(256) void edge_scatter(const int* __restrict__ ei, const int* __restrict__ ety,
                             int E, int* __restrict__ cursor, unsigned* __restrict__ srcet, int Nn){
  const int p = blockIdx.x & 7;
  const int c = blockIdx.x >> 3;
  const int C = gridDim.x >> 3;
  const int chunk = (Nn + 7) >> 3;
  const int lo = p * chunk;
  const int hi = min(Nn, lo + chunk);
  const int per = (E + C - 1) / C;
  const int e1 = min(E, (c + 1) * per);
  for (int e = c * per + threadIdx.x; e < e1; e += 256){
    int dst = ei[E + e];
    if (dst >= lo && dst < hi){
      int pos = atomicAdd(&cursor[dst], 1);
      srcet[pos] = ((unsigned)ety[e] << 16) | (unsigned)ei[e];
    }
  }
}

// ---------------- QKV GEMM (MFMA): Q f16 [N,128]; KV packed [N,64] lanes of [k0,k1,v0,v1] f16 ----------------
__global__ __launch_bounds__(256) void gemm_qkv(const bf16* __restrict__ nfb, const bf16* __restrict__ qeb,
      const bf16* __restrict__ Wcat, const float* __restrict__ bcat,
      short* __restrict__ Qs, short* __restrict__ KVs, int M){
  constexpr int BK=32, LDT=40, K=256;
  __shared__ short As[64*LDT];
  __shared__ short Bs[64*LDT];
  const int tid  = threadIdx.x;
  const int lane = tid & 63;
  const int wave = tid >> 6;
  const int wm = (wave >> 1) * 32, wn = (wave & 1) * 32;
  const long m0 = (long)blockIdx.x * 64;
  const int  n0 = blockIdx.y * 64;
  floatx4 acc00 = {0.f,0.f,0.f,0.f}, acc01 = {0.f,0.f,0.f,0.f};
  floatx4 acc10 = {0.f,0.f,0.f,0.f}, acc11 = {0.f,0.f,0.f,0.f};
  const int srow = tid >> 2, scg = (tid & 3) * 8;
  const int r = lane & 15, q = lane >> 4;
  const short* Ag = (const short*)nfb;
  const short* Qg = (const short*)qeb;
  const short* Bg = (const short*)Wcat;
  for (int k0 = 0; k0 < K; k0 += BK){
    short8 va = {0,0,0,0,0,0,0,0};
    if (k0 < 128){
      long ar = m0 + srow;
      if (ar < M) va = *(const short8*)(Ag + ar*128 + k0 + scg);
    } else {
      va = *(const short8*)(Qg + (k0-128) + scg);   // row-independent broadcast
    }
    *(short8*)(&As[srow*LDT + scg]) = va;
    *(short8*)(&Bs[srow*LDT + scg]) = *(const short8*)(Bg + (long)(n0 + srow)*K + k0 + scg);
    __syncthreads();
    short8 a0 = *(const short8*)(&As[(wm      + r)*LDT + q*8]);
    short8 a1 = *(const short8*)(&As[(wm + 16 + r)*LDT + q*8]);
    short8 b0 = *(const short8*)(&Bs[(wn      + r)*LDT + q*8]);
    short8 b1 = *(const short8*)(&Bs[(wn + 16 + r)*LDT + q*8]);
    acc00 = __builtin_amdgcn_mfma_f32_16x16x32_bf16(a0, b0, acc00, 0, 0, 0);
    acc01 = __builtin_amdgcn_mfma_f32_16x16x32_bf16(a0, b1, acc01, 0, 0, 0);
    acc10 = __builtin_amdgcn_mfma_f32_16x16x32_bf16(a1, b0, acc10, 0, 0, 0);
    acc11 = __builtin_amdgcn_mfma_f32_16x16x32_bf16(a1, b1, acc11, 0, 0, 0);
    __syncthreads();
  }
  #pragma unroll
  for (int i=0;i<2;i++)
  #pragma unroll
  for (int j=0;j<2;j++){
    floatx4 av = (i==0) ? ((j==0)?acc00:acc01) : ((j==0)?acc10:acc11);
    int col = n0 + wn + j*16 + r;
    float bsv = bcat[col];
    #pragma unroll
    for (int g=0; g<4; g++){
      long row = m0 + wm + i*16 + q*4 + g;
      if (row < M){
        short bits = hfbits(av[g] + bsv);
        if (col < 128)      Qs[row*128 + col] = bits;
        else if (col < 256){ int d = col - 128; KVs[row*256 + ((d>>1)<<2) + (d&1)] = bits; }
        else               { int d = col - 256; KVs[row*256 + ((d>>1)<<2) + 2 + (d&1)] = bits; }
      }
    }
  }
}

// ---------------- generic GEMM (MFMA, used for Wo): C f32 = A_bf16 @ B_bf16^T + bias ----------------
__global__ __launch_bounds__(256) void gemm_bt(const bf16* __restrict__ A, const bf16* __restrict__ B,
      const float* __restrict__ bias, float* __restrict__ C, int M, int N, int K){
  constexpr int BK=32, LDT=40;
  __shared__ short As[64*LDT];
  __shared__ short Bs[64*LDT];
  const int tid  = threadIdx.x;
  const int lane = tid & 63;
  const int wave = tid >> 6;
  const int wm = (wave >> 1) * 32, wn = (wave & 1) * 32;
  const long m0 = (long)blockIdx.x * 64;
  const int  n0 = blockIdx.y * 64;
  floatx4 acc00 = {0.f,0.f,0.f,0.f}, acc01 = {0.f,0.f,0.f,0.f};
  floatx4 acc10 = {0.f,0.f,0.f,0.f}, acc11 = {0.f,0.f,0.f,0.f};
  const int srow = tid >> 2, scg = (tid & 3) * 8;
  const int r = lane & 15, q = lane >> 4;
  const short* Ag = (const short*)A;
  const short* Bg = (const short*)B;
  for (int k0 = 0; k0 < K; k0 += BK){
    short8 va = {0,0,0,0,0,0,0,0};
    long ar = m0 + srow;
    if (ar < M) va = *(const short8*)(Ag + ar*K + k0 + scg);
    *(short8*)(&As[srow*LDT + scg]) = va;
    *(short8*)(&Bs[srow*LDT + scg]) = *(const short8*)(Bg + (long)(n0 + srow)*K + k0 + scg);
    __syncthreads();
    short8 a0 = *(const short8*)(&As[(wm      + r)*LDT + q*8]);
    short8 a1 = *(const short8*)(&As[(wm + 16 + r)*LDT + q*8]);
    short8 b0 = *(const short8*)(&Bs[(wn      + r)*LDT + q*8]);
    short8 b1 = *(const short8*)(&Bs[(wn + 16 + r)*LDT + q*8]);
    acc00 = __builtin_amdgcn_mfma_f32_16x16x32_bf16(a0, b0, acc00, 0, 0, 0);
    acc01 = __builtin_amdgcn_mfma_f32_16x16x32_bf16(a0, b1, acc01, 0, 0, 0);
    acc10 = __builtin_amdgcn_mfma_f32_16x16x32_bf16(a1, b0, acc10, 0, 0, 0);
    acc11 = __builtin_amdgcn_mfma_f32_16x16x32_bf16(a1, b1, acc11, 0, 0, 0);
    __syncthreads();
  }
  #pragma unroll
  for (int i=0;i<2;i++)
  #pragma unroll
  for (int j=0;j<2;j++){
    floatx4 av = (i==0) ? ((j==0)?acc00:acc01) : ((j==0)?acc10:acc11);
    int col = n0 + wn + j*16 + r;
    float bsv = bias[col];
    #pragma unroll
    for (int g=0; g<4; g++){
      long row = m0 + wm + i*16 + q*4 + g;
      if (row < M) C[row*(long)N + col] = av[g] + bsv;
    }
  }
}

// ---------------- attention: 1 wave per node, lane owns dims {2l,2l+1} as f16 pairs ----------------
// Edge loop unrolled x4: 4 independent KV-gather + score chains in flight per wave
// to cover L2-miss/L3 latency (counters showed VALUBusy 43%, HBM 32% -> latency-bound).
__global__ __launch_bounds__(256) void attn_agg(const unsigned* __restrict__ Qh,
     const uint2* __restrict__ KVh, const unsigned* __restrict__ Rh,
     const int* __restrict__ rowptr, const unsigned* __restrict__ srcet,
     unsigned* __restrict__ agg, int Nn){
  const int w = threadIdx.x >> 6, l = threadIdx.x & 63;
  const int n = blockIdx.x*4 + w;
  if (n >= Nn) return;
  hf2 q2 = u2h2(Qh[(long)n*64 + l]);
  int beg = rowptr[n], end = rowptr[n+1];
  float acc0 = 0.f, acc1 = 0.f, denom = 0.f;
  for (int c = beg; c < end; c += 64){
    int cnt = end - c; if (cnt > 64) cnt = 64;
    unsigned se_l = (c + l < end) ? srcet[c + l] : 0u;
    int j = 0;
    for (; j + 4 <= cnt; j += 4){
      unsigned se0 = __shfl(se_l, j+0);
      unsigned se1 = __shfl(se_l, j+1);
      unsigned se2 = __shfl(se_l, j+2);
      unsigned se3 = __shfl(se_l, j+3);
      uint2 kv0 = KVh[(long)(se0 & 0xFFFF)*64 + l];
      uint2 kv1 = KVh[(long)(se1 & 0xFFFF)*64 + l];
      uint2 kv2 = KVh[(long)(se2 & 0xFFFF)*64 + l];
      uint2 kv3 = KVh[(long)(se3 & 0xFFFF)*64 + l];
      unsigned r0 = Rh[(se0 >> 16)*64 + l];
      unsigned r1 = Rh[(se1 >> 16)*64 + l];
      unsigned r2 = Rh[(se2 >> 16)*64 + l];
      unsigned r3 = Rh[(se3 >> 16)*64 + l];
      hf2 kb0 = u2h2(kv0.x) + u2h2(r0);
      hf2 kb1 = u2h2(kv1.x) + u2h2(r1);
      hf2 kb2 = u2h2(kv2.x) + u2h2(r2);
      hf2 kb3 = u2h2(kv3.x) + u2h2(r3);
#if __has_builtin(__builtin_amdgcn_fdot2)
      float p0 = __builtin_amdgcn_fdot2(q2, kb0, 0.f, false);
      float p1 = __builtin_amdgcn_fdot2(q2, kb1, 0.f, false);
      float p2 = __builtin_amdgcn_fdot2(q2, kb2, 0.f, false);
      float p3 = __builtin_amdgcn_fdot2(q2, kb3, 0.f, false);
#else
      float p0 = fmaf((float)q2.y, (float)kb0.y, (float)q2.x * (float)kb0.x);
      float p1 = fmaf((float)q2.y, (float)kb1.y, (float)q2.x * (float)kb1.x);
      float p2 = fmaf((float)q2.y, (float)kb2.y, (float)q2.x * (float)kb2.x);
      float p3 = fmaf((float)q2.y, (float)kb3.y, (float)q2.x * (float)kb3.x);
#endif
      p0 += __shfl_xor(p0, 1); p1 += __shfl_xor(p1, 1);
      p2 += __shfl_xor(p2, 1); p3 += __shfl_xor(p3, 1);
      p0 += __shfl_xor(p0, 2); p1 += __shfl_xor(p1, 2);
      p2 += __shfl_xor(p2, 2); p3 += __shfl_xor(p3, 2);
      p0 += __shfl_xor(p0, 4); p1 += __shfl_xor(p1, 4);
      p2 += __shfl_xor(p2, 4); p3 += __shfl_xor(p3, 4);
      float e0 = __expf(p0 * 0.25f);
      float e1 = __expf(p1 * 0.25f);
      float e2 = __expf(p2 * 0.25f);
      float e3 = __expf(p3 * 0.25f);
      denom += e0; denom += e1; denom += e2; denom += e3;
      hf2 v0 = u2h2(kv0.y), v1 = u2h2(kv1.y), v2 = u2h2(kv2.y), v3 = u2h2(kv3.y);
      acc0 = fmaf(e0, (float)v0.x, acc0);
      acc1 = fmaf(e0, (float)v0.y, acc1);
      acc0 = fmaf(e1, (float)v1.x, acc0);
      acc1 = fmaf(e1, (float)v1.y, acc1);
      acc0 = fmaf(e2, (float)v2.x, acc0);
      acc1 = fmaf(e2, (float)v2.y, acc1);
      acc0 = fmaf(e3, (float)v3.x, acc0);
      acc1 = fmaf(e3, (float)v3.y, acc1);
    }
    for (; j < cnt; ++j){
      unsigned se = __shfl(se_l, j);
      int src = se & 0xFFFF;
      int et  = se >> 16;
      uint2 kv = KVh[(long)src*64 + l];
      hf2 kb = u2h2(kv.x) + u2h2(Rh[et*64 + l]);
#if __has_builtin(__builtin_amdgcn_fdot2)
      float p = __builtin_amdgcn_fdot2(q2, kb, 0.f, false);
#else
      float p = fmaf((float)q2.y, (float)kb.y, (float)q2.x * (float)kb.x);
#endif
      p += __shfl_xor(p, 1); p += __shfl_xor(p, 2); p += __shfl_xor(p, 4);
      float es = __expf(p * 0.25f);
      denom += es;
      hf2 v2 = u2h2(kv.y);
      acc0 = fmaf(es, (float)v2.x, acc0);
      acc1 = fmaf(es, (float)v2.y, acc1);
    }
  }
  float inv = 1.f / (denom + 1e-8f);
  unsigned out = ((unsigned)(unsigned short)bfbits(acc1 * inv) << 16)
               |  (unsigned)(unsigned short)bfbits(acc0 * inv);
  agg[(long)n*64 + l] = out;
}

// ---------------- residual + LN1: x = LN(nf + attn), out bf16 ----------------
__global__ __launch_bounds__(128) void ln_add1(const float* __restrict__ nf, const float* __restrict__ attn,
     const float* __restrict__ g, const float* __restrict__ b, bf16* __restrict__ xout){
  long n = blockIdx.x; int t = threadIdx.x;
  float y = nf[n*128 + t] + attn[n*128 + t];
  float s = y, s2 = y*y;
  #pragma unroll
  for (int off=32; off>0; off>>=1){ s += __shfl_xor(s, off); s2 += __shfl_xor(s2, off); }
  __shared__ float ps[4];
  if ((t & 63) == 0){ ps[(t>>6)*2] = s; ps[(t>>6)*2+1] = s2; }
  __syncthreads();
  float tot = ps[0] + ps[2], tot2 = ps[1] + ps[3];
  float mu = tot * (1.f/128.f);
  float var = tot2 * (1.f/128.f) - mu*mu;
  float rs = rsqrtf(var + 1e-5f);
  xout[n*128 + t] = f2b((y - mu)*rs*g[t] + b[t]);
}

// ---------------- fused FFN (MFMA), hidden in 4 quarters of 128 (R3 version, measured 59us) ----------------
// Weights staged through LDS (ds_read->MFMA low latency path; direct-global B
// regressed to 106us in R4: MFMA serialized on vmcnt). LDS 52.7 KB -> 3 blocks/CU.
__global__ __launch_bounds__(256) void ffn_fused(const bf16* __restrict__ X, const bf16* __restrict__ W1,
    const float* __restrict__ b1, const bf16* __restrict__ W2, const float* __restrict__ b2,
    float* __restrict__ Out, int M){
  __shared__ short Xs[64*136];
  __shared__ short Hs[64*140];
  __shared__ short Ws[64*136];   // W1: 64 rows x 136; W2: 128 rows x 68 (8704 shorts exactly)
  const int tid = threadIdx.x, lane = tid & 63, wave = tid >> 6;
  const int r = lane & 15, q = lane >> 4;
  const int wm = (wave >> 1) * 32, wn = (wave & 1) * 32;
  const long m0 = (long)blockIdx.x * 64;
  const short* Xg  = (const short*)X;
  const short* W1g = (const short*)W1;
  const short* W2g = (const short*)W2;
  #pragma unroll
  for (int c=0;c<4;c++){
    int idx = c*256 + tid, row = idx >> 4, ch = (idx & 15) * 8;
    short8 v = {0,0,0,0,0,0,0,0};
    long ar = m0 + row;
    if (ar < M) v = *(const short8*)(Xg + ar*128 + ch);
    *(short8*)(&Xs[row*136 + ch]) = v;
  }
  const int wn2 = (wave & 1) * 64;
  floatx4 o[2][4];
  #pragma unroll
  for (int i=0;i<2;i++)
  #pragma unroll
  for (int j=0;j<4;j++) o[i][j] = (floatx4){0.f,0.f,0.f,0.f};
  for (int qtr = 0; qtr < 4; ++qtr){
    const int hb = qtr * 128;
    // ---- GEMM1: H[:, hb:hb+128] = gelu(X @ W1[hb:hb+128,:]^T + b1) in 2 chunks of 64 cols
    for (int c0 = 0; c0 < 128; c0 += 64){
      #pragma unroll
      for (int c=0;c<4;c++){
        int idx = c*256 + tid, row = idx >> 4, ch = (idx & 15) * 8;
        *(short8*)(&Ws[row*136 + ch]) = *(const short8*)(W1g + (long)(hb + c0 + row)*128 + ch);
      }
      __syncthreads();
      floatx4 h00 = {0.f,0.f,0.f,0.f}, h01 = {0.f,0.f,0.f,0.f};
      floatx4 h10 = {0.f,0.f,0.f,0.f}, h11 = {0.f,0.f,0.f,0.f};
      #pragma unroll
      for (int k0 = 0; k0 < 128; k0 += 32){
        short8 a0 = *(const short8*)(&Xs[(wm      + r)*136 + k0 + q*8]);
        short8 a1 = *(const short8*)(&Xs[(wm + 16 + r)*136 + k0 + q*8]);
        short8 b0 = *(const short8*)(&Ws[(wn      + r)*136 + k0 + q*8]);
        short8 bv = *(const short8*)(&Ws[(wn + 16 + r)*136 + k0 + q*8]);
        h00 = __builtin_amdgcn_mfma_f32_16x16x32_bf16(a0, b0, h00, 0, 0, 0);
        h01 = __builtin_amdgcn_mfma_f32_16x16x32_bf16(a0, bv, h01, 0, 0, 0);
        h10 = __builtin_amdgcn_mfma_f32_16x16x32_bf16(a1, b0, h10, 0, 0, 0);
        h11 = __builtin_amdgcn_mfma_f32_16x16x32_bf16(a1, bv, h11, 0, 0, 0);
      }
      #pragma unroll
      for (int i=0;i<2;i++)
      #pragma unroll
      for (int j=0;j<2;j++){
        floatx4 av = (i==0) ? ((j==0)?h00:h01) : ((j==0)?h10:h11);
        int col = wn + j*16 + r;
        float bb = b1[hb + c0 + col];
        #pragma unroll
        for (int g=0; g<4; g++){
          int row = wm + i*16 + q*4 + g;
          float v = av[g] + bb;
          v = 0.5f * v * (1.f + erff(v * 0.70710678118f));   // exact GELU
          Hs[row*140 + c0 + col] = bfbits(v);
        }
      }
      __syncthreads();
    }
    // ---- GEMM2 partial: o += H_qtr @ W2[:, hb:hb+128]^T in 2 K-chunks of 64
    for (int k0 = 0; k0 < 128; k0 += 64){
      #pragma unroll
      for (int c=0;c<4;c++){
        int idx = c*256 + tid, row = idx >> 3, ch = (idx & 7) * 8;
        *(short8*)(&Ws[row*68 + ch]) = *(const short8*)(W2g + (long)row*512 + hb + k0 + ch);
      }
      __syncthreads();
      #pragma unroll
      for (int ks = 0; ks < 64; ks += 32){
        short8 a0 = *(const short8*)(&Hs[(wm      + r)*140 + k0 + ks + q*8]);
        short8 a1 = *(const short8*)(&Hs[(wm + 16 + r)*140 + k0 + ks + q*8]);
        #pragma unroll
        for (int j=0;j<4;j++){
          short8 bj = *(const short8*)(&Ws[(wn2 + j*16 + r)*68 + ks + q*8]);
          o[0][j] = __builtin_amdgcn_mfma_f32_16x16x32_bf16(a0, bj, o[0][j], 0, 0, 0);
          o[1][j] = __builtin_amdgcn_mfma_f32_16x16x32_bf16(a1, bj, o[1][j], 0, 0, 0);
        }
      }
      __syncthreads();
    }
  }
  #pragma unroll
  for (int i=0;i<2;i++)
  #pragma unroll
  for (int j=0;j<4;j++){
    int col = wn2 + j*16 + r;
    float bb = b2[col];
    #pragma unroll
    for (int g=0; g<4; g++){
      long row = m0 + wm + i*16 + q*4 + g;
      if (row < M) Out[row*128 + col] = o[i][j][g] + bb;
    }
  }
}

// ---------------- residual + LN2: out = LN(x + ffo), f32 out ----------------
__global__ __launch_bounds__(128) void ln_add2(const bf16* __restrict__ X, const float* __restrict__ ffo,
     const float* __restrict__ g, const float* __restrict__ b, float* __restrict__ out){
  long n = blockIdx.x; int t = threadIdx.x;
  float y = b2f(X[n*128 + t]) + ffo[n*128 + t];
  float s = y, s2 = y*y;
  #pragma unroll
  for (int off=32; off>0; off>>=1){ s += __shfl_xor(s, off); s2 += __shfl_xor(s2, off); }
  __shared__ float ps[4];
  if ((t & 63) == 0){ ps[(t>>6)*2] = s; ps[(t>>6)*2+1] = s2; }
  __syncthreads();
  float tot = ps[0] + ps[2], tot2 = ps[1] + ps[3];
  float mu = tot * (1.f/128.f);
  float var = tot2 * (1.f/128.f) - mu*mu;
  float rs = rsqrtf(var + 1e-5f);
  out[n*128 + t] = (y - mu)*rs*g[t] + b[t];
}

// ---------------- relational interaction layer (R=100, naive f32) ----------------
__device__ __forceinline__ float dotf(const float* __restrict__ s, const float* __restrict__ w, int n){
  float acc = 0.f;
  const float4* w4 = (const float4*)w;
  #pragma unroll 4
  for (int j = 0; j < (n >> 2); ++j){
    float4 wv = w4[j];
    acc += s[4*j]*wv.x + s[4*j+1]*wv.y + s[4*j+2]*wv.z + s[4*j+3]*wv.w;
  }
  return acc;
}

__global__ __launch_bounds__(128) void rel_layer(const float* __restrict__ rel, const float* __restrict__ relW,
    const float* __restrict__ relb, const float* __restrict__ Wc, const float* __restrict__ bc,
    const float* __restrict__ gn, const float* __restrict__ bn, float* __restrict__ out){
  int rr = blockIdx.x, t = threadIdx.x;
  __shared__ float rrow[128];
  __shared__ float comb[512];
  rrow[t] = rel[(long)rr*128 + t];
  __syncthreads();
  #pragma unroll
  for (int k=0;k<4;k++){
    comb[k*128 + t] = dotf(rrow, relW + ((long)(k*128) + t)*128, 128) + relb[k*128 + t];
  }
  __syncthreads();
  float c2 = dotf(comb, Wc + (long)t*512, 512) + bc[t];
  float y = rrow[t] + c2;
  float s = y, s2 = y*y;
  #pragma unroll
  for (int off=32; off>0; off>>=1){ s += __shfl_xor(s, off); s2 += __shfl_xor(s2, off); }
  __shared__ float ps[4];
  if ((t & 63) == 0){ ps[(t>>6)*2] = s; ps[(t>>6)*2+1] = s2; }
  __syncthreads();
  float tot = ps[0] + ps[2], tot2 = ps[1] + ps[3];
  float mu = tot * (1.f/128.f);
  float var = tot2 * (1.f/128.f) - mu*mu;
  float rs = rsqrtf(var + 1e-5f);
  out[(long)rr*128 + t] = (y - mu)*rs*gn[t] + bn[t];
}

extern "C" void kernel_launch(void* const* d_in, const int* in_sizes, int n_in,
                              void* d_out, int out_size, void* d_ws, size_t ws_size,
                              hipStream_t stream){
  const int H = 128;
  auto S = [&](int i){ return in_sizes[i]; };
  bool ok = (n_in == 27);
  if (ok){
    ok = ok && S(1)==H && (S(0)%H)==0 && S(2)==2*S(3) && (S(4)%H)==0;
    ok = ok && S(5)==2*H*H && S(7)==2*H*H && S(9)==H*H && S(11)==H*H;
    ok = ok && S(17)==4*H*H && S(19)==4*H*H && S(21)==4*H*H && S(23)==4*H*H;
    ok = ok && out_size == S(0) + S(4);
  }
  if (!ok){
    fill_const<<<(out_size + 255)/256, 256, 0, stream>>>((float*)d_out, 100.0f, out_size);
    return;
  }

  const float* nf   = (const float*)d_in[0];
  const float* qe   = (const float*)d_in[1];
  const int*   ei   = (const int*)  d_in[2];
  const int*   ety  = (const int*)  d_in[3];
  const float* rel  = (const float*)d_in[4];
  const float* Wq   = (const float*)d_in[5];
  const float* bq   = (const float*)d_in[6];
  const float* Wk   = (const float*)d_in[7];
  const float* bk   = (const float*)d_in[8];
  const float* Wv   = (const float*)d_in[9];
  const float* bv   = (const float*)d_in[10];
  const float* Wo   = (const float*)d_in[11];
  const float* bo   = (const float*)d_in[12];
  const float* n1g  = (const float*)d_in[13];
  const float* n1b  = (const float*)d_in[14];
  const float* n2g  = (const float*)d_in[15];
  const float* n2b  = (const float*)d_in[16];
  const float* W1   = (const float*)d_in[17];
  const float* b1   = (const float*)d_in[18];
  const float* W2   = (const float*)d_in[19];
  const float* b2v  = (const float*)d_in[20];
  const float* relW = (const float*)d_in[21];
  const float* relbp= (const float*)d_in[22];
  const float* Wc   = (const float*)d_in[23];
  const float* bc   = (const float*)d_in[24];
  const float* rng  = (const float*)d_in[25];
  const float* rnb  = (const float*)d_in[26];

  const int N = in_sizes[0] / 128;
  const int E = in_sizes[2] / 2;
  const int R = in_sizes[4] / 128;

  char* ws = (char*)d_ws;
  size_t off = 0;
  auto alloc = [&](size_t bytes)->char*{
    char* p = ws + off; off = (off + bytes + 255) & ~(size_t)255; return p;
  };
  // regNA: nfb bf16 [N,128] -> aggp bf16 [N,128] (nfb dead after gemm_qkv)
  char*     regNA  = alloc((size_t)N * 256);
  // regKV: KVh uint2 [N,64] -> attn f32 [N,128] -> ffo f32 [N,128]
  char*     regKV  = alloc((size_t)N * 512);
  unsigned* Qh     = (unsigned*)alloc((size_t)N * 256);   // f16 pairs; dead after attn_agg
  bf16*     xlb    = (bf16*)    alloc((size_t)N * 256);
  bf16*     qeb    = (bf16*)    alloc(256);
  bf16*     Wcat   = (bf16*)    alloc((size_t)384*256*2);
  float*    bcat   = (float*)   alloc(384*4);
  bf16*     Wob    = (bf16*)    alloc((size_t)128*128*2);
  bf16*     W1b    = (bf16*)    alloc((size_t)512*128*2);
  bf16*     W2b    = (bf16*)    alloc((size_t)128*512*2);
  short*    Rh     = (short*)   alloc((size_t)R*128*2);   // rel embeddings f16
  int*      deg    = (int*)     alloc((size_t)N * 4);
  int*      rowptr = (int*)     alloc((size_t)(N+1) * 4);
  int*      cursor = (int*)     alloc((size_t)N * 4);
  unsigned* srcet  = (unsigned*)alloc((size_t)E * 4);
  const int NB = (N + 255) / 256;
  int*      bsum   = (int*)     alloc((size_t)NB * 4);

  if (off > ws_size){
    fill_const<<<(out_size + 255)/256, 256, 0, stream>>>((float*)d_out, 50.0f, out_size);
    return;
  }

  bf16*     nfb  = (bf16*)regNA;
  unsigned* aggp = (unsigned*)regNA;  // bf16 pairs, overlays nfb
  uint2*    KVh  = (uint2*)regKV;
  float*    attn = (float*)regKV;     // overlays KVh (dead after attn_agg)
  float*    ffo  = (float*)regKV;     // overlays attn (dead after ln_add1)
  float*    outx = (float*)d_out;
  float*    outr = (float*)d_out + (size_t)N*128;

  // conversions
  conv_f2b<<<(N*128 + 255)/256, 256, 0, stream>>>(nf, nfb, N*128);
  conv_f2b<<<1, 128, 0, stream>>>(qe, qeb, 128);
  build_wcat<<<(384*256 + 255)/256, 256, 0, stream>>>(Wq, Wk, Wv, bq, bk, bv, Wcat, bcat);
  conv_f2b<<<(128*128 + 255)/256, 256, 0, stream>>>(Wo, Wob, 128*128);
  conv_f2b<<<(512*128 + 255)/256, 256, 0, stream>>>(W1, W1b, 512*128);
  conv_f2b<<<(128*512 + 255)/256, 256, 0, stream>>>(W2, W2b, 128*512);
  conv_f2h<<<(R*128 + 255)/256, 256, 0, stream>>>(rel, Rh, R*128);

  // CSR (hierarchical scan: per-block reduce -> scan block sums -> per-block scan)
  hipMemsetAsync(deg, 0, (size_t)N*4, stream);
  edge_hist<<<(E + 255)/256, 256, 0, stream>>>(ei, E, deg);
  scan_p1<<<NB, 256, 0, stream>>>(deg, N, bsum);
  scan_p2<<<1, 1024, 0, stream>>>(bsum, NB, E, rowptr, N);
  scan_p3<<<NB, 256, 0, stream>>>(deg, bsum, N, rowptr, cursor);
  edge_scatter<<<2048, 256, 0, stream>>>(ei, ety, E, cursor, srcet, N);

  // pipeline
  dim3 g1((N + 63)/64, 6);
  gemm_qkv<<<g1, 256, 0, stream>>>(nfb, qeb, Wcat, bcat, (short*)Qh, (short*)KVh, N);
  attn_agg<<<(N + 3)/4, 256, 0, stream>>>(Qh, KVh, (const unsigned*)Rh, rowptr, srcet, aggp, N);
  dim3 g2((N + 63)/64, 2);
  gemm_bt<<<g2, 256, 0, stream>>>((const bf16*)aggp, Wob, bo, attn, N, 128, 128);
  ln_add1<<<N, 128, 0, stream>>>(nf, attn, n1g, n1b, xlb);
  ffn_fused<<<(N + 63)/64, 256, 0, stream>>>(xlb, W1b, b1, W2b, b2v, ffo, N);
  ln_add2<<<N, 128, 0, stream>>>(xlb, ffo, n2g, n2b, outx);
  rel_layer<<<R, 128, 0, stream>>>(rel, relW, relbp, Wc, bc, rng, rnb, outr);
}

// Round 6
// 426.580 us; speedup vs baseline: 1.1369x; 1.0395x over previous
//
#include <hip/hip_runtime.h>
#include <hip/hip_bf16.h>
#include <math.h>

using bf16 = __hip_bfloat16;
typedef _Float16 hf;
typedef hf __attribute__((ext_vector_type(2))) hf2;
typedef __attribute__((ext_vector_type(8))) short short8;
typedef __attribute__((ext_vector_type(4))) float floatx4;

__device__ __forceinline__ float b2f(bf16 x){ return __bfloat162float(x); }
__device__ __forceinline__ bf16 f2b(float x){ return __float2bfloat16(x); }
__device__ __forceinline__ short bfbits(float x){ bf16 t = __float2bfloat16(x); return *(short*)&t; }
__device__ __forceinline__ short hfbits(float x){ hf t = (hf)x; return *(short*)&t; }
__device__ __forceinline__ hf2 u2h2(unsigned u){ return *(hf2*)&u; }

__global__ void fill_const(float* __restrict__ p, float v, int n){
  int i = blockIdx.x*blockDim.x + threadIdx.x;
  if (i < n) p[i] = v;
}

__global__ void conv_f2b(const float* __restrict__ src, bf16* __restrict__ dst, int n){
  int i = blockIdx.x*blockDim.x + threadIdx.x;
  if (i < n) dst[i] = f2b(src[i]);
}

__global__ void conv_f2h(const float* __restrict__ src, short* __restrict__ dst, int n){
  int i = blockIdx.x*blockDim.x + threadIdx.x;
  if (i < n) dst[i] = hfbits(src[i]);
}

// Wcat bf16 [384,256] = [Wq; Wk; Wv|0], bcat f32 [384]
__global__ void build_wcat(const float* __restrict__ Wq, const float* __restrict__ Wk,
                           const float* __restrict__ Wv, const float* __restrict__ bq,
                           const float* __restrict__ bk, const float* __restrict__ bv,
                           bf16* __restrict__ Wcat, float* __restrict__ bcat){
  int i = blockIdx.x*blockDim.x + threadIdx.x;
  if (i >= 384*256) return;
  int r = i >> 8, c = i & 255;
  float v;
  if (r < 128)       v = Wq[r*256 + c];
  else if (r < 256)  v = Wk[(r-128)*256 + c];
  else               v = (c < 128) ? Wv[(r-256)*128 + c] : 0.f;
  Wcat[i] = f2b(v);
  if (i < 384) bcat[i] = (i < 128) ? bq[i] : (i < 256 ? bk[i-128] : bv[i-256]);
}

// ---------------- CSR build ----------------
__global__ void edge_hist(const int* __restrict__ ei, int E, int* __restrict__ deg){
  int e = blockIdx.x*blockDim.x + threadIdx.x;
  if (e >= E) return;
  atomicAdd(&deg[ei[E + e]], 1);
}

// Hierarchical scan, stage 1: per-block (256-elem) reduce of deg -> bsum[block]
__global__ __launch_bounds__(256) void scan_p1(const int* __restrict__ deg, int Nn,
                                               int* __restrict__ bsum){
  int i = blockIdx.x*256 + threadIdx.x;
  int v = (i < Nn) ? deg[i] : 0;
  #pragma unroll
  for (int off=1; off<64; off<<=1) v += __shfl_xor(v, off);
  __shared__ int ws[4];
  if ((threadIdx.x & 63) == 0) ws[threadIdx.x >> 6] = v;
  __syncthreads();
  if (threadIdx.x == 0) bsum[blockIdx.x] = ws[0] + ws[1] + ws[2] + ws[3];
}

// stage 2: single-block exclusive scan of bsum[NB] in place; also writes rowptr[Nn]=E
__global__ __launch_bounds__(1024) void scan_p2(int* __restrict__ bsum, int NB, int E,
                                                int* __restrict__ rowptr, int Nn){
  __shared__ int wsum[16];
  __shared__ int carry_s;
  if (threadIdx.x == 0) carry_s = 0;
  __syncthreads();
  const int lane = threadIdx.x & 63, w = threadIdx.x >> 6;
  for (int base = 0; base < NB; base += 1024){
    int i = base + threadIdx.x;
    int v = (i < NB) ? bsum[i] : 0;
    int s = v;
    #pragma unroll
    for (int off=1; off<64; off<<=1){ int t = __shfl_up(s, off); if (lane >= off) s += t; }
    if (lane == 63) wsum[w] = s;
    __syncthreads();
    if (threadIdx.x < 16){
      int ws = wsum[threadIdx.x];
      #pragma unroll
      for (int off=1; off<16; off<<=1){ int t = __shfl_up(ws, off); if (threadIdx.x >= off) ws += t; }
      wsum[threadIdx.x] = ws;   // inclusive scan of wave totals
    }
    __syncthreads();
    int carry = carry_s;
    int excl = carry + (w ? wsum[w-1] : 0) + (s - v);
    if (i < NB) bsum[i] = excl;
    __syncthreads();
    if (threadIdx.x == 1023) carry_s = carry + wsum[15];
    __syncthreads();
  }
  if (threadIdx.x == 0) rowptr[Nn] = E;
}

// stage 3: per-block exclusive scan of deg tile + block offset -> rowptr, cursor
__global__ __launch_bounds__(256) void scan_p3(const int* __restrict__ deg,
      const int* __restrict__ boff, int Nn,
      int* __restrict__ rowptr, int* __restrict__ cursor){
  int i = blockIdx.x*256 + threadIdx.x;
  int v = (i < Nn) ? deg[i] : 0;
  const int lane = threadIdx.x & 63, w = threadIdx.x >> 6;
  int s = v;
  #pragma unroll
  for (int off=1; off<64; off<<=1){ int t = __shfl_up(s, off); if (lane >= off) s += t; }
  __shared__ int wsum[4];
  if (lane == 63) wsum[w] = s;
  __syncthreads();
  int wpre = 0;
  #pragma unroll
  for (int k=0;k<4;k++) if (k < w) wpre += wsum[k];
  int excl = boff[blockIdx.x] + wpre + (s - v);
  if (i < Nn){ rowptr[i] = excl; cursor[i] = excl; }
}

// dst-partitioned scatter: 8 node-ranges; pass = bid&7 aligns with round-robin
// block->XCD dispatch so each XCD's L2 owns one ~E/8*4B srcet region (locality
// heuristic only; correctness independent of mapping, G16).
__global__ __launch_bounds__(256) void edge_scatter(const int* __restrict__ ei, const int* __restrict__ ety,
                             int E, int* __restrict__ cursor, unsigned* __restrict__ srcet, int Nn){
  const int p = blockIdx.x & 7;
  const int c = blockIdx.x >> 3;
  const int C = gridDim.x >> 3;
  const int chunk = (Nn + 7) >> 3;
  const int lo = p * chunk;
  const int hi = min(Nn, lo + chunk);
  const int per = (E + C - 1) / C;
  const int e1 = min(E, (c + 1) * per);
  for (int e = c * per + threadIdx.x; e < e1; e += 256){
    int dst = ei[E + e];
    if (dst >= lo && dst < hi){
      int pos = atomicAdd(&cursor[dst], 1);
      srcet[pos] = ((unsigned)ety[e] << 16) | (unsigned)ei[e];
    }
  }
}

// ---------------- QKV GEMM (MFMA): Q f16 [N,128]; KV packed [N,64] lanes of [k0,k1,v0,v1] f16 ----------------
__global__ __launch_bounds__(256) void gemm_qkv(const bf16* __restrict__ nfb, const bf16* __restrict__ qeb,
      const bf16* __restrict__ Wcat, const float* __restrict__ bcat,
      short* __restrict__ Qs, short* __restrict__ KVs, int M){
  constexpr int BK=32, LDT=40, K=256;
  __shared__ short As[64*LDT];
  __shared__ short Bs[64*LDT];
  const int tid  = threadIdx.x;
  const int lane = tid & 63;
  const int wave = tid >> 6;
  const int wm = (wave >> 1) * 32, wn = (wave & 1) * 32;
  const long m0 = (long)blockIdx.x * 64;
  const int  n0 = blockIdx.y * 64;
  floatx4 acc00 = {0.f,0.f,0.f,0.f}, acc01 = {0.f,0.f,0.f,0.f};
  floatx4 acc10 = {0.f,0.f,0.f,0.f}, acc11 = {0.f,0.f,0.f,0.f};
  const int srow = tid >> 2, scg = (tid & 3) * 8;
  const int r = lane & 15, q = lane >> 4;
  const short* Ag = (const short*)nfb;
  const short* Qg = (const short*)qeb;
  const short* Bg = (const short*)Wcat;
  for (int k0 = 0; k0 < K; k0 += BK){
    short8 va = {0,0,0,0,0,0,0,0};
    if (k0 < 128){
      long ar = m0 + srow;
      if (ar < M) va = *(const short8*)(Ag + ar*128 + k0 + scg);
    } else {
      va = *(const short8*)(Qg + (k0-128) + scg);   // row-independent broadcast
    }
    *(short8*)(&As[srow*LDT + scg]) = va;
    *(short8*)(&Bs[srow*LDT + scg]) = *(const short8*)(Bg + (long)(n0 + srow)*K + k0 + scg);
    __syncthreads();
    short8 a0 = *(const short8*)(&As[(wm      + r)*LDT + q*8]);
    short8 a1 = *(const short8*)(&As[(wm + 16 + r)*LDT + q*8]);
    short8 b0 = *(const short8*)(&Bs[(wn      + r)*LDT + q*8]);
    short8 b1 = *(const short8*)(&Bs[(wn + 16 + r)*LDT + q*8]);
    acc00 = __builtin_amdgcn_mfma_f32_16x16x32_bf16(a0, b0, acc00, 0, 0, 0);
    acc01 = __builtin_amdgcn_mfma_f32_16x16x32_bf16(a0, b1, acc01, 0, 0, 0);
    acc10 = __builtin_amdgcn_mfma_f32_16x16x32_bf16(a1, b0, acc10, 0, 0, 0);
    acc11 = __builtin_amdgcn_mfma_f32_16x16x32_bf16(a1, b1, acc11, 0, 0, 0);
    __syncthreads();
  }
  #pragma unroll
  for (int i=0;i<2;i++)
  #pragma unroll
  for (int j=0;j<2;j++){
    floatx4 av = (i==0) ? ((j==0)?acc00:acc01) : ((j==0)?acc10:acc11);
    int col = n0 + wn + j*16 + r;
    float bsv = bcat[col];
    #pragma unroll
    for (int g=0; g<4; g++){
      long row = m0 + wm + i*16 + q*4 + g;
      if (row < M){
        short bits = hfbits(av[g] + bsv);
        if (col < 128)      Qs[row*128 + col] = bits;
        else if (col < 256){ int d = col - 128; KVs[row*256 + ((d>>1)<<2) + (d&1)] = bits; }
        else               { int d = col - 256; KVs[row*256 + ((d>>1)<<2) + 2 + (d&1)] = bits; }
      }
    }
  }
}

// ---------------- Wo GEMM + residual + LN1 fused: xlb = LN(nf + agg@Wo^T + bo) ----------------
// Block owns 64 rows x ALL 128 cols (waves: wm=(w>>1)*32 rows, wn2=(w&1)*64 cols)
// so the row-wise LN reduction stays in-block: 16-lane shuffle + cross-wave LDS.
__global__ __launch_bounds__(256) void gemm_bt_ln(const bf16* __restrict__ A, const bf16* __restrict__ B,
      const float* __restrict__ bias, const float* __restrict__ nf,
      const float* __restrict__ gam, const float* __restrict__ bet,
      bf16* __restrict__ xout, int M){
  __shared__ short As[64*136];
  __shared__ short Bs[128*136];
  const int tid = threadIdx.x, lane = tid & 63, wave = tid >> 6;
  const int r = lane & 15, q = lane >> 4;
  const int wm = (wave >> 1) * 32, wn2 = (wave & 1) * 64;
  const long m0 = (long)blockIdx.x * 64;
  const short* Ag = (const short*)A;
  const short* Bg = (const short*)B;
  #pragma unroll
  for (int c=0;c<4;c++){
    int idx = c*256 + tid, row = idx >> 4, ch = (idx & 15) * 8;
    short8 v = {0,0,0,0,0,0,0,0};
    long ar = m0 + row;
    if (ar < M) v = *(const short8*)(Ag + ar*128 + ch);
    *(short8*)(&As[row*136 + ch]) = v;
  }
  #pragma unroll
  for (int c=0;c<8;c++){
    int idx = c*256 + tid, row = idx >> 4, ch = (idx & 15) * 8;
    *(short8*)(&Bs[row*136 + ch]) = *(const short8*)(Bg + (long)row*128 + ch);
  }
  __syncthreads();
  floatx4 o[2][4];
  #pragma unroll
  for (int i=0;i<2;i++)
  #pragma unroll
  for (int j=0;j<4;j++) o[i][j] = (floatx4){0.f,0.f,0.f,0.f};
  #pragma unroll
  for (int k0 = 0; k0 < 128; k0 += 32){
    short8 a0 = *(const short8*)(&As[(wm      + r)*136 + k0 + q*8]);
    short8 a1 = *(const short8*)(&As[(wm + 16 + r)*136 + k0 + q*8]);
    #pragma unroll
    for (int j=0;j<4;j++){
      short8 bj = *(const short8*)(&Bs[(wn2 + j*16 + r)*136 + k0 + q*8]);
      o[0][j] = __builtin_amdgcn_mfma_f32_16x16x32_bf16(a0, bj, o[0][j], 0, 0, 0);
      o[1][j] = __builtin_amdgcn_mfma_f32_16x16x32_bf16(a1, bj, o[1][j], 0, 0, 0);
    }
  }
  __syncthreads();          // Bs dead -> reuse as reduction scratch
  float* redp = (float*)Bs; // [64 rows][2 halves][2] = 256 floats
  float* stat = redp + 256; // [64 rows][2] = 128 floats
  // y = nf + o + bias, per-thread partials over the 64 cols this wave owns
  float yv[2][4][4];
  #pragma unroll
  for (int i=0;i<2;i++){
    #pragma unroll
    for (int j=0;j<4;j++){
      int col = wn2 + j*16 + r;
      float bsv = bias[col];
      #pragma unroll
      for (int g=0; g<4; g++){
        int row = wm + i*16 + q*4 + g;
        long grow = m0 + row;
        float nfv = (grow < M) ? nf[grow*128 + col] : 0.f;
        yv[i][j][g] = o[i][j][g] + bsv + nfv;
      }
    }
  }
  #pragma unroll
  for (int i=0;i<2;i++){
    #pragma unroll
    for (int g=0; g<4; g++){
      float s  = yv[i][0][g] + yv[i][1][g] + yv[i][2][g] + yv[i][3][g];
      float s2 = yv[i][0][g]*yv[i][0][g] + yv[i][1][g]*yv[i][1][g]
               + yv[i][2][g]*yv[i][2][g] + yv[i][3][g]*yv[i][3][g];
      #pragma unroll
      for (int m=1; m<16; m<<=1){ s += __shfl_xor(s, m); s2 += __shfl_xor(s2, m); }
      if (r == 0){
        int row = wm + i*16 + q*4 + g;
        redp[row*4 + (wave & 1)*2 + 0] = s;
        redp[row*4 + (wave & 1)*2 + 1] = s2;
      }
    }
  }
  __syncthreads();
  if (tid < 64){
    float s  = redp[tid*4 + 0] + redp[tid*4 + 2];
    float s2 = redp[tid*4 + 1] + redp[tid*4 + 3];
    float mu = s * (1.f/128.f);
    float var = s2 * (1.f/128.f) - mu*mu;
    stat[tid*2 + 0] = mu;
    stat[tid*2 + 1] = rsqrtf(var + 1e-5f);
  }
  __syncthreads();
  #pragma unroll
  for (int i=0;i<2;i++){
    #pragma unroll
    for (int j=0;j<4;j++){
      int col = wn2 + j*16 + r;
      float gv = gam[col], bv = bet[col];
      #pragma unroll
      for (int g=0; g<4; g++){
        int row = wm + i*16 + q*4 + g;
        long grow = m0 + row;
        if (grow < M){
          float mu = stat[row*2], rs = stat[row*2 + 1];
          xout[grow*128 + col] = f2b((yv[i][j][g] - mu)*rs*gv + bv);
        }
      }
    }
  }
}

// ---------------- attention: 1 wave per node, lane owns dims {2l,2l+1} as f16 pairs ----------------
// Edge loop unrolled x4: 4 independent KV-gather + score chains in flight per wave.
__global__ __launch_bounds__(256) void attn_agg(const unsigned* __restrict__ Qh,
     const uint2* __restrict__ KVh, const unsigned* __restrict__ Rh,
     const int* __restrict__ rowptr, const unsigned* __restrict__ srcet,
     unsigned* __restrict__ agg, int Nn){
  const int w = threadIdx.x >> 6, l = threadIdx.x & 63;
  const int n = blockIdx.x*4 + w;
  if (n >= Nn) return;
  hf2 q2 = u2h2(Qh[(long)n*64 + l]);
  int beg = rowptr[n], end = rowptr[n+1];
  float acc0 = 0.f, acc1 = 0.f, denom = 0.f;
  for (int c = beg; c < end; c += 64){
    int cnt = end - c; if (cnt > 64) cnt = 64;
    unsigned se_l = (c + l < end) ? srcet[c + l] : 0u;
    int j = 0;
    for (; j + 4 <= cnt; j += 4){
      unsigned se0 = __shfl(se_l, j+0);
      unsigned se1 = __shfl(se_l, j+1);
      unsigned se2 = __shfl(se_l, j+2);
      unsigned se3 = __shfl(se_l, j+3);
      uint2 kv0 = KVh[(long)(se0 & 0xFFFF)*64 + l];
      uint2 kv1 = KVh[(long)(se1 & 0xFFFF)*64 + l];
      uint2 kv2 = KVh[(long)(se2 & 0xFFFF)*64 + l];
      uint2 kv3 = KVh[(long)(se3 & 0xFFFF)*64 + l];
      unsigned r0 = Rh[(se0 >> 16)*64 + l];
      unsigned r1 = Rh[(se1 >> 16)*64 + l];
      unsigned r2 = Rh[(se2 >> 16)*64 + l];
      unsigned r3 = Rh[(se3 >> 16)*64 + l];
      hf2 kb0 = u2h2(kv0.x) + u2h2(r0);
      hf2 kb1 = u2h2(kv1.x) + u2h2(r1);
      hf2 kb2 = u2h2(kv2.x) + u2h2(r2);
      hf2 kb3 = u2h2(kv3.x) + u2h2(r3);
#if __has_builtin(__builtin_amdgcn_fdot2)
      float p0 = __builtin_amdgcn_fdot2(q2, kb0, 0.f, false);
      float p1 = __builtin_amdgcn_fdot2(q2, kb1, 0.f, false);
      float p2 = __builtin_amdgcn_fdot2(q2, kb2, 0.f, false);
      float p3 = __builtin_amdgcn_fdot2(q2, kb3, 0.f, false);
#else
      float p0 = fmaf((float)q2.y, (float)kb0.y, (float)q2.x * (float)kb0.x);
      float p1 = fmaf((float)q2.y, (float)kb1.y, (float)q2.x * (float)kb1.x);
      float p2 = fmaf((float)q2.y, (float)kb2.y, (float)q2.x * (float)kb2.x);
      float p3 = fmaf((float)q2.y, (float)kb3.y, (float)q2.x * (float)kb3.x);
#endif
      p0 += __shfl_xor(p0, 1); p1 += __shfl_xor(p1, 1);
      p2 += __shfl_xor(p2, 1); p3 += __shfl_xor(p3, 1);
      p0 += __shfl_xor(p0, 2); p1 += __shfl_xor(p1, 2);
      p2 += __shfl_xor(p2, 2); p3 += __shfl_xor(p3, 2);
      p0 += __shfl_xor(p0, 4); p1 += __shfl_xor(p1, 4);
      p2 += __shfl_xor(p2, 4); p3 += __shfl_xor(p3, 4);
      float e0 = __expf(p0 * 0.25f);
      float e1 = __expf(p1 * 0.25f);
      float e2 = __expf(p2 * 0.25f);
      float e3 = __expf(p3 * 0.25f);
      denom += e0; denom += e1; denom += e2; denom += e3;
      hf2 v0 = u2h2(kv0.y), v1 = u2h2(kv1.y), v2 = u2h2(kv2.y), v3 = u2h2(kv3.y);
      acc0 = fmaf(e0, (float)v0.x, acc0);
      acc1 = fmaf(e0, (float)v0.y, acc1);
      acc0 = fmaf(e1, (float)v1.x, acc0);
      acc1 = fmaf(e1, (float)v1.y, acc1);
      acc0 = fmaf(e2, (float)v2.x, acc0);
      acc1 = fmaf(e2, (float)v2.y, acc1);
      acc0 = fmaf(e3, (float)v3.x, acc0);
      acc1 = fmaf(e3, (float)v3.y, acc1);
    }
    for (; j < cnt; ++j){
      unsigned se = __shfl(se_l, j);
      int src = se & 0xFFFF;
      int et  = se >> 16;
      uint2 kv = KVh[(long)src*64 + l];
      hf2 kb = u2h2(kv.x) + u2h2(Rh[et*64 + l]);
#if __has_builtin(__builtin_amdgcn_fdot2)
      float p = __builtin_amdgcn_fdot2(q2, kb, 0.f, false);
#else
      float p = fmaf((float)q2.y, (float)kb.y, (float)q2.x * (float)kb.x);
#endif
      p += __shfl_xor(p, 1); p += __shfl_xor(p, 2); p += __shfl_xor(p, 4);
      float es = __expf(p * 0.25f);
      denom += es;
      hf2 v2 = u2h2(kv.y);
      acc0 = fmaf(es, (float)v2.x, acc0);
      acc1 = fmaf(es, (float)v2.y, acc1);
    }
  }
  float inv = 1.f / (denom + 1e-8f);
  unsigned out = ((unsigned)(unsigned short)bfbits(acc1 * inv) << 16)
               |  (unsigned)(unsigned short)bfbits(acc0 * inv);
  agg[(long)n*64 + l] = out;
}

// ---------------- fused FFN (MFMA) + residual + LN2 epilogue ----------------
// R3 weight-LDS structure (59us). Residual x is ALREADY in Xs -> fuse
// out = LN(x + ffn) in the epilogue; reduction scratch overlays dead Ws.
__global__ __launch_bounds__(256) void ffn_fused(const bf16* __restrict__ X, const bf16* __restrict__ W1,
    const float* __restrict__ b1, const bf16* __restrict__ W2, const float* __restrict__ b2,
    const float* __restrict__ gam, const float* __restrict__ bet,
    float* __restrict__ Out, int M){
  __shared__ short Xs[64*136];
  __shared__ short Hs[64*140];
  __shared__ short Ws[64*136];   // W1: 64x136; W2: 128x68; epilogue: reduction scratch
  const int tid = threadIdx.x, lane = tid & 63, wave = tid >> 6;
  const int r = lane & 15, q = lane >> 4;
  const int wm = (wave >> 1) * 32, wn = (wave & 1) * 32;
  const long m0 = (long)blockIdx.x * 64;
  const short* Xg  = (const short*)X;
  const short* W1g = (const short*)W1;
  const short* W2g = (const short*)W2;
  #pragma unroll
  for (int c=0;c<4;c++){
    int idx = c*256 + tid, row = idx >> 4, ch = (idx & 15) * 8;
    short8 v = {0,0,0,0,0,0,0,0};
    long ar = m0 + row;
    if (ar < M) v = *(const short8*)(Xg + ar*128 + ch);
    *(short8*)(&Xs[row*136 + ch]) = v;
  }
  const int wn2 = (wave & 1) * 64;
  floatx4 o[2][4];
  #pragma unroll
  for (int i=0;i<2;i++)
  #pragma unroll
  for (int j=0;j<4;j++) o[i][j] = (floatx4){0.f,0.f,0.f,0.f};
  for (int qtr = 0; qtr < 4; ++qtr){
    const int hb = qtr * 128;
    // ---- GEMM1: H[:, hb:hb+128] = gelu(X @ W1[hb:hb+128,:]^T + b1) in 2 chunks of 64 cols
    for (int c0 = 0; c0 < 128; c0 += 64){
      #pragma unroll
      for (int c=0;c<4;c++){
        int idx = c*256 + tid, row = idx >> 4, ch = (idx & 15) * 8;
        *(short8*)(&Ws[row*136 + ch]) = *(const short8*)(W1g + (long)(hb + c0 + row)*128 + ch);
      }
      __syncthreads();
      floatx4 h00 = {0.f,0.f,0.f,0.f}, h01 = {0.f,0.f,0.f,0.f};
      floatx4 h10 = {0.f,0.f,0.f,0.f}, h11 = {0.f,0.f,0.f,0.f};
      #pragma unroll
      for (int k0 = 0; k0 < 128; k0 += 32){
        short8 a0 = *(const short8*)(&Xs[(wm      + r)*136 + k0 + q*8]);
        short8 a1 = *(const short8*)(&Xs[(wm + 16 + r)*136 + k0 + q*8]);
        short8 b0 = *(const short8*)(&Ws[(wn      + r)*136 + k0 + q*8]);
        short8 bv = *(const short8*)(&Ws[(wn + 16 + r)*136 + k0 + q*8]);
        h00 = __builtin_amdgcn_mfma_f32_16x16x32_bf16(a0, b0, h00, 0, 0, 0);
        h01 = __builtin_amdgcn_mfma_f32_16x16x32_bf16(a0, bv, h01, 0, 0, 0);
        h10 = __builtin_amdgcn_mfma_f32_16x16x32_bf16(a1, b0, h10, 0, 0, 0);
        h11 = __builtin_amdgcn_mfma_f32_16x16x32_bf16(a1, bv, h11, 0, 0, 0);
      }
      #pragma unroll
      for (int i=0;i<2;i++)
      #pragma unroll
      for (int j=0;j<2;j++){
        floatx4 av = (i==0) ? ((j==0)?h00:h01) : ((j==0)?h10:h11);
        int col = wn + j*16 + r;
        float bb = b1[hb + c0 + col];
        #pragma unroll
        for (int g=0; g<4; g++){
          int row = wm + i*16 + q*4 + g;
          float v = av[g] + bb;
          v = 0.5f * v * (1.f + erff(v * 0.70710678118f));   // exact GELU
          Hs[row*140 + c0 + col] = bfbits(v);
        }
      }
      __syncthreads();
    }
    // ---- GEMM2 partial: o += H_qtr @ W2[:, hb:hb+128]^T in 2 K-chunks of 64
    for (int k0 = 0; k0 < 128; k0 += 64){
      #pragma unroll
      for (int c=0;c<4;c++){
        int idx = c*256 + tid, row = idx >> 3, ch = (idx & 7) * 8;
        *(short8*)(&Ws[row*68 + ch]) = *(const short8*)(W2g + (long)row*512 + hb + k0 + ch);
      }
      __syncthreads();
      #pragma unroll
      for (int ks = 0; ks < 64; ks += 32){
        short8 a0 = *(const short8*)(&Hs[(wm      + r)*140 + k0 + ks + q*8]);
        short8 a1 = *(const short8*)(&Hs[(wm + 16 + r)*140 + k0 + ks + q*8]);
        #pragma unroll
        for (int j=0;j<4;j++){
          short8 bj = *(const short8*)(&Ws[(wn2 + j*16 + r)*68 + ks + q*8]);
          o[0][j] = __builtin_amdgcn_mfma_f32_16x16x32_bf16(a0, bj, o[0][j], 0, 0, 0);
          o[1][j] = __builtin_amdgcn_mfma_f32_16x16x32_bf16(a1, bj, o[1][j], 0, 0, 0);
        }
      }
      __syncthreads();
    }
  }
  // ---- epilogue: out = LN(x + ffn + b2); x is resident in Xs (bf16)
  float* redp = (float*)Ws; // Ws dead (barrier above); [64][2][2] floats
  float* stat = redp + 256; // [64][2]
  float yv[2][4][4];
  #pragma unroll
  for (int i=0;i<2;i++){
    #pragma unroll
    for (int j=0;j<4;j++){
      int col = wn2 + j*16 + r;
      float bb = b2[col];
      #pragma unroll
      for (int g=0; g<4; g++){
        int row = wm + i*16 + q*4 + g;
        float xr = b2f(*(const bf16*)&Xs[row*136 + col]);
        yv[i][j][g] = o[i][j][g] + bb + xr;
      }
    }
  }
  #pragma unroll
  for (int i=0;i<2;i++){
    #pragma unroll
    for (int g=0; g<4; g++){
      float s  = yv[i][0][g] + yv[i][1][g] + yv[i][2][g] + yv[i][3][g];
      float s2 = yv[i][0][g]*yv[i][0][g] + yv[i][1][g]*yv[i][1][g]
               + yv[i][2][g]*yv[i][2][g] + yv[i][3][g]*yv[i][3][g];
      #pragma unroll
      for (int m=1; m<16; m<<=1){ s += __shfl_xor(s, m); s2 += __shfl_xor(s2, m); }
      if (r == 0){
        int row = wm + i*16 + q*4 + g;
        redp[row*4 + (wave & 1)*2 + 0] = s;
        redp[row*4 + (wave & 1)*2 + 1] = s2;
      }
    }
  }
  __syncthreads();
  if (tid < 64){
    float s  = redp[tid*4 + 0] + redp[tid*4 + 2];
    float s2 = redp[tid*4 + 1] + redp[tid*4 + 3];
    float mu = s * (1.f/128.f);
    float var = s2 * (1.f/128.f) - mu*mu;
    stat[tid*2 + 0] = mu;
    stat[tid*2 + 1] = rsqrtf(var + 1e-5f);
  }
  __syncthreads();
  #pragma unroll
  for (int i=0;i<2;i++){
    #pragma unroll
    for (int j=0;j<4;j++){
      int col = wn2 + j*16 + r;
      float gv = gam[col], bv = bet[col];
      #pragma unroll
      for (int g=0; g<4; g++){
        int row = wm + i*16 + q*4 + g;
        long grow = m0 + row;
        if (grow < M){
          float mu = stat[row*2], rs = stat[row*2 + 1];
          Out[grow*128 + col] = (yv[i][j][g] - mu)*rs*gv + bv;
        }
      }
    }
  }
}

// ---------------- relational interaction layer (R=100, naive f32) ----------------
__device__ __forceinline__ float dotf(const float* __restrict__ s, const float* __restrict__ w, int n){
  float acc = 0.f;
  const float4* w4 = (const float4*)w;
  #pragma unroll 4
  for (int j = 0; j < (n >> 2); ++j){
    float4 wv = w4[j];
    acc += s[4*j]*wv.x + s[4*j+1]*wv.y + s[4*j+2]*wv.z + s[4*j+3]*wv.w;
  }
  return acc;
}

__global__ __launch_bounds__(128) void rel_layer(const float* __restrict__ rel, const float* __restrict__ relW,
    const float* __restrict__ relb, const float* __restrict__ Wc, const float* __restrict__ bc,
    const float* __restrict__ gn, const float* __restrict__ bn, float* __restrict__ out){
  int rr = blockIdx.x, t = threadIdx.x;
  __shared__ float rrow[128];
  __shared__ float comb[512];
  rrow[t] = rel[(long)rr*128 + t];
  __syncthreads();
  #pragma unroll
  for (int k=0;k<4;k++){
    comb[k*128 + t] = dotf(rrow, relW + ((long)(k*128) + t)*128, 128) + relb[k*128 + t];
  }
  __syncthreads();
  float c2 = dotf(comb, Wc + (long)t*512, 512) + bc[t];
  float y = rrow[t] + c2;
  float s = y, s2 = y*y;
  #pragma unroll
  for (int off=32; off>0; off>>=1){ s += __shfl_xor(s, off); s2 += __shfl_xor(s2, off); }
  __shared__ float ps[4];
  if ((t & 63) == 0){ ps[(t>>6)*2] = s; ps[(t>>6)*2+1] = s2; }
  __syncthreads();
  float tot = ps[0] + ps[2], tot2 = ps[1] + ps[3];
  float mu = tot * (1.f/128.f);
  float var = tot2 * (1.f/128.f) - mu*mu;
  float rs = rsqrtf(var + 1e-5f);
  out[(long)rr*128 + t] = (y - mu)*rs*gn[t] + bn[t];
}

extern "C" void kernel_launch(void* const* d_in, const int* in_sizes, int n_in,
                              void* d_out, int out_size, void* d_ws, size_t ws_size,
                              hipStream_t stream){
  const int H = 128;
  auto S = [&](int i){ return in_sizes[i]; };
  bool ok = (n_in == 27);
  if (ok){
    ok = ok && S(1)==H && (S(0)%H)==0 && S(2)==2*S(3) && (S(4)%H)==0;
    ok = ok && S(5)==2*H*H && S(7)==2*H*H && S(9)==H*H && S(11)==H*H;
    ok = ok && S(17)==4*H*H && S(19)==4*H*H && S(21)==4*H*H && S(23)==4*H*H;
    ok = ok && out_size == S(0) + S(4);
  }
  if (!ok){
    fill_const<<<(out_size + 255)/256, 256, 0, stream>>>((float*)d_out, 100.0f, out_size);
    return;
  }

  const float* nf   = (const float*)d_in[0];
  const float* qe   = (const float*)d_in[1];
  const int*   ei   = (const int*)  d_in[2];
  const int*   ety  = (const int*)  d_in[3];
  const float* rel  = (const float*)d_in[4];
  const float* Wq   = (const float*)d_in[5];
  const float* bq   = (const float*)d_in[6];
  const float* Wk   = (const float*)d_in[7];
  const float* bk   = (const float*)d_in[8];
  const float* Wv   = (const float*)d_in[9];
  const float* bv   = (const float*)d_in[10];
  const float* Wo   = (const float*)d_in[11];
  const float* bo   = (const float*)d_in[12];
  const float* n1g  = (const float*)d_in[13];
  const float* n1b  = (const float*)d_in[14];
  const float* n2g  = (const float*)d_in[15];
  const float* n2b  = (const float*)d_in[16];
  const float* W1   = (const float*)d_in[17];
  const float* b1   = (const float*)d_in[18];
  const float* W2   = (const float*)d_in[19];
  const float* b2v  = (const float*)d_in[20];
  const float* relW = (const float*)d_in[21];
  const float* relbp= (const float*)d_in[22];
  const float* Wc   = (const float*)d_in[23];
  const float* bc   = (const float*)d_in[24];
  const float* rng  = (const float*)d_in[25];
  const float* rnb  = (const float*)d_in[26];

  const int N = in_sizes[0] / 128;
  const int E = in_sizes[2] / 2;
  const int R = in_sizes[4] / 128;

  char* ws = (char*)d_ws;
  size_t off = 0;
  auto alloc = [&](size_t bytes)->char*{
    char* p = ws + off; off = (off + bytes + 255) & ~(size_t)255; return p;
  };
  // regNA: nfb bf16 [N,128] -> aggp bf16 [N,128] (nfb dead after gemm_qkv)
  char*     regNA  = alloc((size_t)N * 256);
  // regKV: KVh uint2 [N,64] (dead after attn_agg)
  char*     regKV  = alloc((size_t)N * 512);
  unsigned* Qh     = (unsigned*)alloc((size_t)N * 256);   // f16 pairs; dead after attn_agg
  bf16*     xlb    = (bf16*)    alloc((size_t)N * 256);
  bf16*     qeb    = (bf16*)    alloc(256);
  bf16*     Wcat   = (bf16*)    alloc((size_t)384*256*2);
  float*    bcat   = (float*)   alloc(384*4);
  bf16*     Wob    = (bf16*)    alloc((size_t)128*128*2);
  bf16*     W1b    = (bf16*)    alloc((size_t)512*128*2);
  bf16*     W2b    = (bf16*)    alloc((size_t)128*512*2);
  short*    Rh     = (short*)   alloc((size_t)R*128*2);   // rel embeddings f16
  int*      deg    = (int*)     alloc((size_t)N * 4);
  int*      rowptr = (int*)     alloc((size_t)(N+1) * 4);
  int*      cursor = (int*)     alloc((size_t)N * 4);
  unsigned* srcet  = (unsigned*)alloc((size_t)E * 4);
  const int NB = (N + 255) / 256;
  int*      bsum   = (int*)     alloc((size_t)NB * 4);

  if (off > ws_size){
    fill_const<<<(out_size + 255)/256, 256, 0, stream>>>((float*)d_out, 50.0f, out_size);
    return;
  }

  bf16*     nfb  = (bf16*)regNA;
  unsigned* aggp = (unsigned*)regNA;  // bf16 pairs, overlays nfb
  uint2*    KVh  = (uint2*)regKV;
  float*    outx = (float*)d_out;
  float*    outr = (float*)d_out + (size_t)N*128;

  // conversions
  conv_f2b<<<(N*128 + 255)/256, 256, 0, stream>>>(nf, nfb, N*128);
  conv_f2b<<<1, 128, 0, stream>>>(qe, qeb, 128);
  build_wcat<<<(384*256 + 255)/256, 256, 0, stream>>>(Wq, Wk, Wv, bq, bk, bv, Wcat, bcat);
  conv_f2b<<<(128*128 + 255)/256, 256, 0, stream>>>(Wo, Wob, 128*128);
  conv_f2b<<<(512*128 + 255)/256, 256, 0, stream>>>(W1, W1b, 512*128);
  conv_f2b<<<(128*512 + 255)/256, 256, 0, stream>>>(W2, W2b, 128*512);
  conv_f2h<<<(R*128 + 255)/256, 256, 0, stream>>>(rel, Rh, R*128);

  // CSR (hierarchical scan: per-block reduce -> scan block sums -> per-block scan)
  hipMemsetAsync(deg, 0, (size_t)N*4, stream);
  edge_hist<<<(E + 255)/256, 256, 0, stream>>>(ei, E, deg);
  scan_p1<<<NB, 256, 0, stream>>>(deg, N, bsum);
  scan_p2<<<1, 1024, 0, stream>>>(bsum, NB, E, rowptr, N);
  scan_p3<<<NB, 256, 0, stream>>>(deg, bsum, N, rowptr, cursor);
  edge_scatter<<<2048, 256, 0, stream>>>(ei, ety, E, cursor, srcet, N);

  // pipeline
  dim3 g1((N + 63)/64, 6);
  gemm_qkv<<<g1, 256, 0, stream>>>(nfb, qeb, Wcat, bcat, (short*)Qh, (short*)KVh, N);
  attn_agg<<<(N + 3)/4, 256, 0, stream>>>(Qh, KVh, (const unsigned*)Rh, rowptr, srcet, aggp, N);
  gemm_bt_ln<<<(N + 63)/64, 256, 0, stream>>>((const bf16*)aggp, Wob, bo, nf, n1g, n1b, xlb, N);
  ffn_fused<<<(N + 63)/64, 256, 0, stream>>>(xlb, W1b, b1, W2b, b2v, n2g, n2b, outx, N);
  rel_layer<<<R, 128, 0, stream>>>(rel, relW, relbp, Wc, bc, rng, rnb, outr);
}

// Round 8
// 411.838 us; speedup vs baseline: 1.1776x; 1.0358x over previous
//
#include <hip/hip_runtime.h>
#include <hip/hip_bf16.h>
#include <math.h>

using bf16 = __hip_bfloat16;
typedef _Float16 hf;
typedef hf __attribute__((ext_vector_type(2))) hf2;
typedef __attribute__((ext_vector_type(8))) short short8;
typedef __attribute__((ext_vector_type(4))) short short4v;
typedef __attribute__((ext_vector_type(4))) float floatx4;

__device__ __forceinline__ float b2f(bf16 x){ return __bfloat162float(x); }
__device__ __forceinline__ bf16 f2b(float x){ return __float2bfloat16(x); }
__device__ __forceinline__ short bfbits(float x){ bf16 t = __float2bfloat16(x); return *(short*)&t; }
__device__ __forceinline__ short hfbits(float x){ hf t = (hf)x; return *(short*)&t; }
__device__ __forceinline__ hf2 u2h2(unsigned u){ return *(hf2*)&u; }

__global__ void fill_const(float* __restrict__ p, float v, int n){
  int i = blockIdx.x*blockDim.x + threadIdx.x;
  if (i < n) p[i] = v;
}

// ---------------- fused preprocessing: all dtype conversions + Wcat build + deg zero ----------------
// One dispatch replaces 7 conv kernels + hipMemsetAsync (18 -> 11 dispatches/iter).
// Block ranges: [0,b_nf) nf->bf16 x4-vectorized | wcat | qe | Wo | W1 | W2 | rel->f16 | deg=0
__global__ __launch_bounds__(256) void prep_all(
    const float* __restrict__ nf, bf16* __restrict__ nfb, int n_nf,
    const float* __restrict__ qe, bf16* __restrict__ qeb,
    const float* __restrict__ Wq, const float* __restrict__ Wk, const float* __restrict__ Wv,
    const float* __restrict__ bq, const float* __restrict__ bk, const float* __restrict__ bv,
    bf16* __restrict__ Wcat, float* __restrict__ bcat,
    const float* __restrict__ Wo, bf16* __restrict__ Wob,
    const float* __restrict__ W1, bf16* __restrict__ W1b,
    const float* __restrict__ W2, bf16* __restrict__ W2b,
    const float* __restrict__ rel, short* __restrict__ Rh, int n_rel,
    int* __restrict__ deg, int Nn,
    int b_nf, int b_wcat, int b_wo, int b_w1, int b_w2, int b_rel, int b_deg){
  int b = blockIdx.x, t = threadIdx.x;
  if (b < b_nf){
    int i = (b*256 + t) * 4;
    if (i < n_nf){
      float4 v = *(const float4*)(nf + i);
      short4v o;
      o.x = bfbits(v.x); o.y = bfbits(v.y); o.z = bfbits(v.z); o.w = bfbits(v.w);
      *(short4v*)((short*)nfb + i) = o;
    }
    return;
  }
  b -= b_nf;
  if (b < b_wcat){
    int i = b*256 + t;   // 384*256 elems
    int r = i >> 8, c = i & 255;
    float v;
    if (r < 128)       v = Wq[r*256 + c];
    else if (r < 256)  v = Wk[(r-128)*256 + c];
    else               v = (c < 128) ? Wv[(r-256)*128 + c] : 0.f;
    Wcat[i] = f2b(v);
    if (i < 384) bcat[i] = (i < 128) ? bq[i] : (i < 256 ? bk[i-128] : bv[i-256]);
    return;
  }
  b -= b_wcat;
  if (b < 1){
    if (t < 128) qeb[t] = f2b(qe[t]);
    return;
  }
  b -= 1;
  if (b < b_wo){ int i = b*256 + t; Wob[i] = f2b(Wo[i]); return; }
  b -= b_wo;
  if (b < b_w1){ int i = b*256 + t; W1b[i] = f2b(W1[i]); return; }
  b -= b_w1;
  if (b < b_w2){ int i = b*256 + t; W2b[i] = f2b(W2[i]); return; }
  b -= b_w2;
  if (b < b_rel){ int i = b*256 + t; if (i < n_rel) Rh[i] = hfbits(rel[i]); return; }
  b -= b_rel;
  { int i = b*256 + t; if (i < Nn) deg[i] = 0; }
}

// ---------------- CSR build ----------------
__global__ void edge_hist(const int* __restrict__ ei, int E, int* __restrict__ deg){
  int e = blockIdx.x*blockDim.x + threadIdx.x;
  if (e >= E) return;
  atomicAdd(&deg[ei[E + e]], 1);
}

// Hierarchical scan, stage 1: per-block (256-elem) reduce of deg -> bsum[block]
__global__ __launch_bounds__(256) void scan_p1(const int* __restrict__ deg, int Nn,
                                               int* __restrict__ bsum){
  int i = blockIdx.x*256 + threadIdx.x;
  int v = (i < Nn) ? deg[i] : 0;
  #pragma unroll
  for (int off=1; off<64; off<<=1) v += __shfl_xor(v, off);
  __shared__ int ws[4];
  if ((threadIdx.x & 63) == 0) ws[threadIdx.x >> 6] = v;
  __syncthreads();
  if (threadIdx.x == 0) bsum[blockIdx.x] = ws[0] + ws[1] + ws[2] + ws[3];
}

// stage 2: single-block exclusive scan of bsum[NB] in place; also writes rowptr[Nn]=E
__global__ __launch_bounds__(1024) void scan_p2(int* __restrict__ bsum, int NB, int E,
                                                int* __restrict__ rowptr, int Nn){
  __shared__ int wsum[16];
  __shared__ int carry_s;
  if (threadIdx.x == 0) carry_s = 0;
  __syncthreads();
  const int lane = threadIdx.x & 63, w = threadIdx.x >> 6;
  for (int base = 0; base < NB; base += 1024){
    int i = base + threadIdx.x;
    int v = (i < NB) ? bsum[i] : 0;
    int s = v;
    #pragma unroll
    for (int off=1; off<64; off<<=1){ int t = __shfl_up(s, off); if (lane >= off) s += t; }
    if (lane == 63) wsum[w] = s;
    __syncthreads();
    if (threadIdx.x < 16){
      int ws = wsum[threadIdx.x];
      #pragma unroll
      for (int off=1; off<16; off<<=1){ int t = __shfl_up(ws, off); if (threadIdx.x >= off) ws += t; }
      wsum[threadIdx.x] = ws;   // inclusive scan of wave totals
    }
    __syncthreads();
    int carry = carry_s;
    int excl = carry + (w ? wsum[w-1] : 0) + (s - v);
    if (i < NB) bsum[i] = excl;
    __syncthreads();
    if (threadIdx.x == 1023) carry_s = carry + wsum[15];
    __syncthreads();
  }
  if (threadIdx.x == 0) rowptr[Nn] = E;
}

// stage 3: per-block exclusive scan of deg tile + block offset -> rowptr, cursor
__global__ __launch_bounds__(256) void scan_p3(const int* __restrict__ deg,
      const int* __restrict__ boff, int Nn,
      int* __restrict__ rowptr, int* __restrict__ cursor){
  int i = blockIdx.x*256 + threadIdx.x;
  int v = (i < Nn) ? deg[i] : 0;
  const int lane = threadIdx.x & 63, w = threadIdx.x >> 6;
  int s = v;
  #pragma unroll
  for (int off=1; off<64; off<<=1){ int t = __shfl_up(s, off); if (lane >= off) s += t; }
  __shared__ int wsum[4];
  if (lane == 63) wsum[w] = s;
  __syncthreads();
  int wpre = 0;
  #pragma unroll
  for (int k=0;k<4;k++) if (k < w) wpre += wsum[k];
  int excl = boff[blockIdx.x] + wpre + (s - v);
  if (i < Nn){ rowptr[i] = excl; cursor[i] = excl; }
}

// dst-partitioned scatter: 8 node-ranges; pass = bid&7 aligns with round-robin
// block->XCD dispatch so each XCD's L2 owns one ~E/8*4B srcet region (locality
// heuristic only; correctness independent of mapping, G16).
__global__ __launch_bounds__(256) void edge_scatter(const int* __restrict__ ei, const int* __restrict__ ety,
                             int E, int* __restrict__ cursor, unsigned* __restrict__ srcet, int Nn){
  const int p = blockIdx.x & 7;
  const int c = blockIdx.x >> 3;
  const int C = gridDim.x >> 3;
  const int chunk = (Nn + 7) >> 3;
  const int lo = p * chunk;
  const int hi = min(Nn, lo + chunk);
  const int per = (E + C - 1) / C;
  const int e1 = min(E, (c + 1) * per);
  for (int e = c * per + threadIdx.x; e < e1; e += 256){
    int dst = ei[E + e];
    if (dst >= lo && dst < hi){
      int pos = atomicAdd(&cursor[dst], 1);
      srcet[pos] = ((unsigned)ety[e] << 16) | (unsigned)ei[e];
    }
  }
}

// ---------------- QKV GEMM (MFMA): Q f16 [N,128]; KV packed [N,64] lanes of [k0,k1,v0,v1] f16 ----------------
__global__ __launch_bounds__(256) void gemm_qkv(const bf16* __restrict__ nfb, const bf16* __restrict__ qeb,
      const bf16* __restrict__ Wcat, const float* __restrict__ bcat,
      short* __restrict__ Qs, short* __restrict__ KVs, int M){
  constexpr int BK=32, LDT=40, K=256;
  __shared__ short As[64*LDT];
  __shared__ short Bs[64*LDT];
  const int tid  = threadIdx.x;
  const int lane = tid & 63;
  const int wave = tid >> 6;
  const int wm = (wave >> 1) * 32, wn = (wave & 1) * 32;
  const long m0 = (long)blockIdx.x * 64;
  const int  n0 = blockIdx.y * 64;
  floatx4 acc00 = {0.f,0.f,0.f,0.f}, acc01 = {0.f,0.f,0.f,0.f};
  floatx4 acc10 = {0.f,0.f,0.f,0.f}, acc11 = {0.f,0.f,0.f,0.f};
  const int srow = tid >> 2, scg = (tid & 3) * 8;
  const int r = lane & 15, q = lane >> 4;
  const short* Ag = (const short*)nfb;
  const short* Qg = (const short*)qeb;
  const short* Bg = (const short*)Wcat;
  for (int k0 = 0; k0 < K; k0 += BK){
    short8 va = {0,0,0,0,0,0,0,0};
    if (k0 < 128){
      long ar = m0 + srow;
      if (ar < M) va = *(const short8*)(Ag + ar*128 + k0 + scg);
    } else {
      va = *(const short8*)(Qg + (k0-128) + scg);   // row-independent broadcast
    }
    *(short8*)(&As[srow*LDT + scg]) = va;
    *(short8*)(&Bs[srow*LDT + scg]) = *(const short8*)(Bg + (long)(n0 + srow)*K + k0 + scg);
    __syncthreads();
    short8 a0 = *(const short8*)(&As[(wm      + r)*LDT + q*8]);
    short8 a1 = *(const short8*)(&As[(wm + 16 + r)*LDT + q*8]);
    short8 b0 = *(const short8*)(&Bs[(wn      + r)*LDT + q*8]);
    short8 b1 = *(const short8*)(&Bs[(wn + 16 + r)*LDT + q*8]);
    acc00 = __builtin_amdgcn_mfma_f32_16x16x32_bf16(a0, b0, acc00, 0, 0, 0);
    acc01 = __builtin_amdgcn_mfma_f32_16x16x32_bf16(a0, b1, acc01, 0, 0, 0);
    acc10 = __builtin_amdgcn_mfma_f32_16x16x32_bf16(a1, b0, acc10, 0, 0, 0);
    acc11 = __builtin_amdgcn_mfma_f32_16x16x32_bf16(a1, b1, acc11, 0, 0, 0);
    __syncthreads();
  }
  #pragma unroll
  for (int i=0;i<2;i++)
  #pragma unroll
  for (int j=0;j<2;j++){
    floatx4 av = (i==0) ? ((j==0)?acc00:acc01) : ((j==0)?acc10:acc11);
    int col = n0 + wn + j*16 + r;
    float bsv = bcat[col];
    #pragma unroll
    for (int g=0; g<4; g++){
      long row = m0 + wm + i*16 + q*4 + g;
      if (row < M){
        short bits = hfbits(av[g] + bsv);
        if (col < 128)      Qs[row*128 + col] = bits;
        else if (col < 256){ int d = col - 128; KVs[row*256 + ((d>>1)<<2) + (d&1)] = bits; }
        else               { int d = col - 256; KVs[row*256 + ((d>>1)<<2) + 2 + (d&1)] = bits; }
      }
    }
  }
}

// ---------------- Wo GEMM + residual + LN1 fused: xlb = LN(nf + agg@Wo^T + bo) ----------------
__global__ __launch_bounds__(256) void gemm_bt_ln(const bf16* __restrict__ A, const bf16* __restrict__ B,
      const float* __restrict__ bias, const float* __restrict__ nf,
      const float* __restrict__ gam, const float* __restrict__ bet,
      bf16* __restrict__ xout, int M){
  __shared__ short As[64*136];
  __shared__ short Bs[128*136];
  const int tid = threadIdx.x, lane = tid & 63, wave = tid >> 6;
  const int r = lane & 15, q = lane >> 4;
  const int wm = (wave >> 1) * 32, wn2 = (wave & 1) * 64;
  const long m0 = (long)blockIdx.x * 64;
  const short* Ag = (const short*)A;
  const short* Bg = (const short*)B;
  #pragma unroll
  for (int c=0;c<4;c++){
    int idx = c*256 + tid, row = idx >> 4, ch = (idx & 15) * 8;
    short8 v = {0,0,0,0,0,0,0,0};
    long ar = m0 + row;
    if (ar < M) v = *(const short8*)(Ag + ar*128 + ch);
    *(short8*)(&As[row*136 + ch]) = v;
  }
  #pragma unroll
  for (int c=0;c<8;c++){
    int idx = c*256 + tid, row = idx >> 4, ch = (idx & 15) * 8;
    *(short8*)(&Bs[row*136 + ch]) = *(const short8*)(Bg + (long)row*128 + ch);
  }
  __syncthreads();
  floatx4 o[2][4];
  #pragma unroll
  for (int i=0;i<2;i++)
  #pragma unroll
  for (int j=0;j<4;j++) o[i][j] = (floatx4){0.f,0.f,0.f,0.f};
  #pragma unroll
  for (int k0 = 0; k0 < 128; k0 += 32){
    short8 a0 = *(const short8*)(&As[(wm      + r)*136 + k0 + q*8]);
    short8 a1 = *(const short8*)(&As[(wm + 16 + r)*136 + k0 + q*8]);
    #pragma unroll
    for (int j=0;j<4;j++){
      short8 bj = *(const short8*)(&Bs[(wn2 + j*16 + r)*136 + k0 + q*8]);
      o[0][j] = __builtin_amdgcn_mfma_f32_16x16x32_bf16(a0, bj, o[0][j], 0, 0, 0);
      o[1][j] = __builtin_amdgcn_mfma_f32_16x16x32_bf16(a1, bj, o[1][j], 0, 0, 0);
    }
  }
  __syncthreads();          // Bs dead -> reuse as reduction scratch
  float* redp = (float*)Bs; // [64 rows][2 halves][2] = 256 floats
  float* stat = redp + 256; // [64 rows][2] = 128 floats
  float yv[2][4][4];
  #pragma unroll
  for (int i=0;i<2;i++){
    #pragma unroll
    for (int j=0;j<4;j++){
      int col = wn2 + j*16 + r;
      float bsv = bias[col];
      #pragma unroll
      for (int g=0; g<4; g++){
        int row = wm + i*16 + q*4 + g;
        long grow = m0 + row;
        float nfv = (grow < M) ? nf[grow*128 + col] : 0.f;
        yv[i][j][g] = o[i][j][g] + bsv + nfv;
      }
    }
  }
  #pragma unroll
  for (int i=0;i<2;i++){
    #pragma unroll
    for (int g=0; g<4; g++){
      float s  = yv[i][0][g] + yv[i][1][g] + yv[i][2][g] + yv[i][3][g];
      float s2 = yv[i][0][g]*yv[i][0][g] + yv[i][1][g]*yv[i][1][g]
               + yv[i][2][g]*yv[i][2][g] + yv[i][3][g]*yv[i][3][g];
      #pragma unroll
      for (int m=1; m<16; m<<=1){ s += __shfl_xor(s, m); s2 += __shfl_xor(s2, m); }
      if (r == 0){
        int row = wm + i*16 + q*4 + g;
        redp[row*4 + (wave & 1)*2 + 0] = s;
        redp[row*4 + (wave & 1)*2 + 1] = s2;
      }
    }
  }
  __syncthreads();
  if (tid < 64){
    float s  = redp[tid*4 + 0] + redp[tid*4 + 2];
    float s2 = redp[tid*4 + 1] + redp[tid*4 + 3];
    float mu = s * (1.f/128.f);
    float var = s2 * (1.f/128.f) - mu*mu;
    stat[tid*2 + 0] = mu;
    stat[tid*2 + 1] = rsqrtf(var + 1e-5f);
  }
  __syncthreads();
  #pragma unroll
  for (int i=0;i<2;i++){
    #pragma unroll
    for (int j=0;j<4;j++){
      int col = wn2 + j*16 + r;
      float gv = gam[col], bv = bet[col];
      #pragma unroll
      for (int g=0; g<4; g++){
        int row = wm + i*16 + q*4 + g;
        long grow = m0 + row;
        if (grow < M){
          float mu = stat[row*2], rs = stat[row*2 + 1];
          xout[grow*128 + col] = f2b((yv[i][j][g] - mu)*rs*gv + bv);
        }
      }
    }
  }
}

// ---------------- attention: 1 wave per node, lane owns dims {2l,2l+1} as f16 pairs ----------------
__global__ __launch_bounds__(256) void attn_agg(const unsigned* __restrict__ Qh,
     const uint2* __restrict__ KVh, const unsigned* __restrict__ Rh,
     const int* __restrict__ rowptr, const unsigned* __restrict__ srcet,
     unsigned* __restrict__ agg, int Nn){
  const int w = threadIdx.x >> 6, l = threadIdx.x & 63;
  const int n = blockIdx.x*4 + w;
  if (n >= Nn) return;
  hf2 q2 = u2h2(Qh[(long)n*64 + l]);
  int beg = rowptr[n], end = rowptr[n+1];
  float acc0 = 0.f, acc1 = 0.f, denom = 0.f;
  for (int c = beg; c < end; c += 64){
    int cnt = end - c; if (cnt > 64) cnt = 64;
    unsigned se_l = (c + l < end) ? srcet[c + l] : 0u;
    int j = 0;
    for (; j + 4 <= cnt; j += 4){
      unsigned se0 = __shfl(se_l, j+0);
      unsigned se1 = __shfl(se_l, j+1);
      unsigned se2 = __shfl(se_l, j+2);
      unsigned se3 = __shfl(se_l, j+3);
      uint2 kv0 = KVh[(long)(se0 & 0xFFFF)*64 + l];
      uint2 kv1 = KVh[(long)(se1 & 0xFFFF)*64 + l];
      uint2 kv2 = KVh[(long)(se2 & 0xFFFF)*64 + l];
      uint2 kv3 = KVh[(long)(se3 & 0xFFFF)*64 + l];
      unsigned r0 = Rh[(se0 >> 16)*64 + l];
      unsigned r1 = Rh[(se1 >> 16)*64 + l];
      unsigned r2 = Rh[(se2 >> 16)*64 + l];
      unsigned r3 = Rh[(se3 >> 16)*64 + l];
      hf2 kb0 = u2h2(kv0.x) + u2h2(r0);
      hf2 kb1 = u2h2(kv1.x) + u2h2(r1);
      hf2 kb2 = u2h2(kv2.x) + u2h2(r2);
      hf2 kb3 = u2h2(kv3.x) + u2h2(r3);
#if __has_builtin(__builtin_amdgcn_fdot2)
      float p0 = __builtin_amdgcn_fdot2(q2, kb0, 0.f, false);
      float p1 = __builtin_amdgcn_fdot2(q2, kb1, 0.f, false);
      float p2 = __builtin_amdgcn_fdot2(q2, kb2, 0.f, false);
      float p3 = __builtin_amdgcn_fdot2(q2, kb3, 0.f, false);
#else
      float p0 = fmaf((float)q2.y, (float)kb0.y, (float)q2.x * (float)kb0.x);
      float p1 = fmaf((float)q2.y, (float)kb1.y, (float)q2.x * (float)kb1.x);
      float p2 = fmaf((float)q2.y, (float)kb2.y, (float)q2.x * (float)kb2.x);
      float p3 = fmaf((float)q2.y, (float)kb3.y, (float)q2.x * (float)kb3.x);
#endif
      p0 += __shfl_xor(p0, 1); p1 += __shfl_xor(p1, 1);
      p2 += __shfl_xor(p2, 1); p3 += __shfl_xor(p3, 1);
      p0 += __shfl_xor(p0, 2); p1 += __shfl_xor(p1, 2);
      p2 += __shfl_xor(p2, 2); p3 += __shfl_xor(p3, 2);
      p0 += __shfl_xor(p0, 4); p1 += __shfl_xor(p1, 4);
      p2 += __shfl_xor(p2, 4); p3 += __shfl_xor(p3, 4);
      float e0 = __expf(p0 * 0.25f);
      float e1 = __expf(p1 * 0.25f);
      float e2 = __expf(p2 * 0.25f);
      float e3 = __expf(p3 * 0.25f);
      denom += e0; denom += e1; denom += e2; denom += e3;
      hf2 v0 = u2h2(kv0.y), v1 = u2h2(kv1.y), v2 = u2h2(kv2.y), v3 = u2h2(kv3.y);
      acc0 = fmaf(e0, (float)v0.x, acc0);
      acc1 = fmaf(e0, (float)v0.y, acc1);
      acc0 = fmaf(e1, (float)v1.x, acc0);
      acc1 = fmaf(e1, (float)v1.y, acc1);
      acc0 = fmaf(e2, (float)v2.x, acc0);
      acc1 = fmaf(e2, (float)v2.y, acc1);
      acc0 = fmaf(e3, (float)v3.x, acc0);
      acc1 = fmaf(e3, (float)v3.y, acc1);
    }
    for (; j < cnt; ++j){
      unsigned se = __shfl(se_l, j);
      int src = se & 0xFFFF;
      int et  = se >> 16;
      uint2 kv = KVh[(long)src*64 + l];
      hf2 kb = u2h2(kv.x) + u2h2(Rh[et*64 + l]);
#if __has_builtin(__builtin_amdgcn_fdot2)
      float p = __builtin_amdgcn_fdot2(q2, kb, 0.f, false);
#else
      float p = fmaf((float)q2.y, (float)kb.y, (float)q2.x * (float)kb.x);
#endif
      p += __shfl_xor(p, 1); p += __shfl_xor(p, 2); p += __shfl_xor(p, 4);
      float es = __expf(p * 0.25f);
      denom += es;
      hf2 v2 = u2h2(kv.y);
      acc0 = fmaf(es, (float)v2.x, acc0);
      acc1 = fmaf(es, (float)v2.y, acc1);
    }
  }
  float inv = 1.f / (denom + 1e-8f);
  unsigned out = ((unsigned)(unsigned short)bfbits(acc1 * inv) << 16)
               |  (unsigned)(unsigned short)bfbits(acc0 * inv);
  agg[(long)n*64 + l] = out;
}

// ---------------- fused FFN (MFMA) + residual + LN2 epilogue ----------------
__global__ __launch_bounds__(256) void ffn_fused(const bf16* __restrict__ X, const bf16* __restrict__ W1,
    const float* __restrict__ b1, const bf16* __restrict__ W2, const float* __restrict__ b2,
    const float* __restrict__ gam, const float* __restrict__ bet,
    float* __restrict__ Out, int M){
  __shared__ short Xs[64*136];
  __shared__ short Hs[64*140];
  __shared__ short Ws[64*136];   // W1: 64x136; W2: 128x68; epilogue: reduction scratch
  const int tid = threadIdx.x, lane = tid & 63, wave = tid >> 6;
  const int r = lane & 15, q = lane >> 4;
  const int wm = (wave >> 1) * 32, wn = (wave & 1) * 32;
  const long m0 = (long)blockIdx.x * 64;
  const short* Xg  = (const short*)X;
  const short* W1g = (const short*)W1;
  const short* W2g = (const short*)W2;
  #pragma unroll
  for (int c=0;c<4;c++){
    int idx = c*256 + tid, row = idx >> 4, ch = (idx & 15) * 8;
    short8 v = {0,0,0,0,0,0,0,0};
    long ar = m0 + row;
    if (ar < M) v = *(const short8*)(Xg + ar*128 + ch);
    *(short8*)(&Xs[row*136 + ch]) = v;
  }
  const int wn2 = (wave & 1) * 64;
  floatx4 o[2][4];
  #pragma unroll
  for (int i=0;i<2;i++)
  #pragma unroll
  for (int j=0;j<4;j++) o[i][j] = (floatx4){0.f,0.f,0.f,0.f};
  for (int qtr = 0; qtr < 4; ++qtr){
    const int hb = qtr * 128;
    for (int c0 = 0; c0 < 128; c0 += 64){
      #pragma unroll
      for (int c=0;c<4;c++){
        int idx = c*256 + tid, row = idx >> 4, ch = (idx & 15) * 8;
        *(short8*)(&Ws[row*136 + ch]) = *(const short8*)(W1g + (long)(hb + c0 + row)*128 + ch);
      }
      __syncthreads();
      floatx4 h00 = {0.f,0.f,0.f,0.f}, h01 = {0.f,0.f,0.f,0.f};
      floatx4 h10 = {0.f,0.f,0.f,0.f}, h11 = {0.f,0.f,0.f,0.f};
      #pragma unroll
      for (int k0 = 0; k0 < 128; k0 += 32){
        short8 a0 = *(const short8*)(&Xs[(wm      + r)*136 + k0 + q*8]);
        short8 a1 = *(const short8*)(&Xs[(wm + 16 + r)*136 + k0 + q*8]);
        short8 b0 = *(const short8*)(&Ws[(wn      + r)*136 + k0 + q*8]);
        short8 bv = *(const short8*)(&Ws[(wn + 16 + r)*136 + k0 + q*8]);
        h00 = __builtin_amdgcn_mfma_f32_16x16x32_bf16(a0, b0, h00, 0, 0, 0);
        h01 = __builtin_amdgcn_mfma_f32_16x16x32_bf16(a0, bv, h01, 0, 0, 0);
        h10 = __builtin_amdgcn_mfma_f32_16x16x32_bf16(a1, b0, h10, 0, 0, 0);
        h11 = __builtin_amdgcn_mfma_f32_16x16x32_bf16(a1, bv, h11, 0, 0, 0);
      }
      #pragma unroll
      for (int i=0;i<2;i++)
      #pragma unroll
      for (int j=0;j<2;j++){
        floatx4 av = (i==0) ? ((j==0)?h00:h01) : ((j==0)?h10:h11);
        int col = wn + j*16 + r;
        float bb = b1[hb + c0 + col];
        #pragma unroll
        for (int g=0; g<4; g++){
          int row = wm + i*16 + q*4 + g;
          float v = av[g] + bb;
          v = 0.5f * v * (1.f + erff(v * 0.70710678118f));   // exact GELU
          Hs[row*140 + c0 + col] = bfbits(v);
        }
      }
      __syncthreads();
    }
    for (int k0 = 0; k0 < 128; k0 += 64){
      #pragma unroll
      for (int c=0;c<4;c++){
        int idx = c*256 + tid, row = idx >> 3, ch = (idx & 7) * 8;
        *(short8*)(&Ws[row*68 + ch]) = *(const short8*)(W2g + (long)row*512 + hb + k0 + ch);
      }
      __syncthreads();
      #pragma unroll
      for (int ks = 0; ks < 64; ks += 32){
        short8 a0 = *(const short8*)(&Hs[(wm      + r)*140 + k0 + ks + q*8]);
        short8 a1 = *(const short8*)(&Hs[(wm + 16 + r)*140 + k0 + ks + q*8]);
        #pragma unroll
        for (int j=0;j<4;j++){
          short8 bj = *(const short8*)(&Ws[(wn2 + j*16 + r)*68 + ks + q*8]);
          o[0][j] = __builtin_amdgcn_mfma_f32_16x16x32_bf16(a0, bj, o[0][j], 0, 0, 0);
          o[1][j] = __builtin_amdgcn_mfma_f32_16x16x32_bf16(a1, bj, o[1][j], 0, 0, 0);
        }
      }
      __syncthreads();
    }
  }
  // ---- epilogue: out = LN(x + ffn + b2); x is resident in Xs (bf16)
  float* redp = (float*)Ws;
  float* stat = redp + 256;
  float yv[2][4][4];
  #pragma unroll
  for (int i=0;i<2;i++){
    #pragma unroll
    for (int j=0;j<4;j++){
      int col = wn2 + j*16 + r;
      float bb = b2[col];
      #pragma unroll
      for (int g=0; g<4; g++){
        int row = wm + i*16 + q*4 + g;
        float xr = b2f(*(const bf16*)&Xs[row*136 + col]);
        yv[i][j][g] = o[i][j][g] + bb + xr;
      }
    }
  }
  #pragma unroll
  for (int i=0;i<2;i++){
    #pragma unroll
    for (int g=0; g<4; g++){
      float s  = yv[i][0][g] + yv[i][1][g] + yv[i][2][g] + yv[i][3][g];
      float s2 = yv[i][0][g]*yv[i][0][g] + yv[i][1][g]*yv[i][1][g]
               + yv[i][2][g]*yv[i][2][g] + yv[i][3][g]*yv[i][3][g];
      #pragma unroll
      for (int m=1; m<16; m<<=1){ s += __shfl_xor(s, m); s2 += __shfl_xor(s2, m); }
      if (r == 0){
        int row = wm + i*16 + q*4 + g;
        redp[row*4 + (wave & 1)*2 + 0] = s;
        redp[row*4 + (wave & 1)*2 + 1] = s2;
      }
    }
  }
  __syncthreads();
  if (tid < 64){
    float s  = redp[tid*4 + 0] + redp[tid*4 + 2];
    float s2 = redp[tid*4 + 1] + redp[tid*4 + 3];
    float mu = s * (1.f/128.f);
    float var = s2 * (1.f/128.f) - mu*mu;
    stat[tid*2 + 0] = mu;
    stat[tid*2 + 1] = rsqrtf(var + 1e-5f);
  }
  __syncthreads();
  #pragma unroll
  for (int i=0;i<2;i++){
    #pragma unroll
    for (int j=0;j<4;j++){
      int col = wn2 + j*16 + r;
      float gv = gam[col], bv = bet[col];
      #pragma unroll
      for (int g=0; g<4; g++){
        int row = wm + i*16 + q*4 + g;
        long grow = m0 + row;
        if (grow < M){
          float mu = stat[row*2], rs = stat[row*2 + 1];
          Out[grow*128 + col] = (yv[i][j][g] - mu)*rs*gv + bv;
        }
      }
    }
  }
}

// ---------------- relational interaction layer (R=100, naive f32) ----------------
__device__ __forceinline__ float dotf(const float* __restrict__ s, const float* __restrict__ w, int n){
  float acc = 0.f;
  const float4* w4 = (const float4*)w;
  #pragma unroll 4
  for (int j = 0; j < (n >> 2); ++j){
    float4 wv = w4[j];
    acc += s[4*j]*wv.x + s[4*j+1]*wv.y + s[4*j+2]*wv.z + s[4*j+3]*wv.w;
  }
  return acc;
}

__global__ __launch_bounds__(128) void rel_layer(const float* __restrict__ rel, const float* __restrict__ relW,
    const float* __restrict__ relb, const float* __restrict__ Wc, const float* __restrict__ bc,
    const float* __restrict__ gn, const float* __restrict__ bn, float* __restrict__ out){
  int rr = blockIdx.x, t = threadIdx.x;
  __shared__ float rrow[128];
  __shared__ float comb[512];
  rrow[t] = rel[(long)rr*128 + t];
  __syncthreads();
  #pragma unroll
  for (int k=0;k<4;k++){
    comb[k*128 + t] = dotf(rrow, relW + ((long)(k*128) + t)*128, 128) + relb[k*128 + t];
  }
  __syncthreads();
  float c2 = dotf(comb, Wc + (long)t*512, 512) + bc[t];
  float y = rrow[t] + c2;
  float s = y, s2 = y*y;
  #pragma unroll
  for (int off=32; off>0; off>>=1){ s += __shfl_xor(s, off); s2 += __shfl_xor(s2, off); }
  __shared__ float ps[4];
  if ((t & 63) == 0){ ps[(t>>6)*2] = s; ps[(t>>6)*2+1] = s2; }
  __syncthreads();
  float tot = ps[0] + ps[2], tot2 = ps[1] + ps[3];
  float mu = tot * (1.f/128.f);
  float var = tot2 * (1.f/128.f) - mu*mu;
  float rs = rsqrtf(var + 1e-5f);
  out[(long)rr*128 + t] = (y - mu)*rs*gn[t] + bn[t];
}

extern "C" void kernel_launch(void* const* d_in, const int* in_sizes, int n_in,
                              void* d_out, int out_size, void* d_ws, size_t ws_size,
                              hipStream_t stream){
  const int H = 128;
  auto S = [&](int i){ return in_sizes[i]; };
  bool ok = (n_in == 27);
  if (ok){
    ok = ok && S(1)==H && (S(0)%H)==0 && S(2)==2*S(3) && (S(4)%H)==0;
    ok = ok && S(5)==2*H*H && S(7)==2*H*H && S(9)==H*H && S(11)==H*H;
    ok = ok && S(17)==4*H*H && S(19)==4*H*H && S(21)==4*H*H && S(23)==4*H*H;
    ok = ok && out_size == S(0) + S(4);
  }
  if (!ok){
    fill_const<<<(out_size + 255)/256, 256, 0, stream>>>((float*)d_out, 100.0f, out_size);
    return;
  }

  const float* nf   = (const float*)d_in[0];
  const float* qe   = (const float*)d_in[1];
  const int*   ei   = (const int*)  d_in[2];
  const int*   ety  = (const int*)  d_in[3];
  const float* rel  = (const float*)d_in[4];
  const float* Wq   = (const float*)d_in[5];
  const float* bq   = (const float*)d_in[6];
  const float* Wk   = (const float*)d_in[7];
  const float* bk   = (const float*)d_in[8];
  const float* Wv   = (const float*)d_in[9];
  const float* bv   = (const float*)d_in[10];
  const float* Wo   = (const float*)d_in[11];
  const float* bo   = (const float*)d_in[12];
  const float* n1g  = (const float*)d_in[13];
  const float* n1b  = (const float*)d_in[14];
  const float* n2g  = (const float*)d_in[15];
  const float* n2b  = (const float*)d_in[16];
  const float* W1   = (const float*)d_in[17];
  const float* b1   = (const float*)d_in[18];
  const float* W2   = (const float*)d_in[19];
  const float* b2v  = (const float*)d_in[20];
  const float* relW = (const float*)d_in[21];
  const float* relbp= (const float*)d_in[22];
  const float* Wc   = (const float*)d_in[23];
  const float* bc   = (const float*)d_in[24];
  const float* rng  = (const float*)d_in[25];
  const float* rnb  = (const float*)d_in[26];

  const int N = in_sizes[0] / 128;
  const int E = in_sizes[2] / 2;
  const int R = in_sizes[4] / 128;

  char* ws = (char*)d_ws;
  size_t off = 0;
  auto alloc = [&](size_t bytes)->char*{
    char* p = ws + off; off = (off + bytes + 255) & ~(size_t)255; return p;
  };
  // regNA: nfb bf16 [N,128] -> aggp bf16 [N,128] (nfb dead after gemm_qkv)
  char*     regNA  = alloc((size_t)N * 256);
  // regKV: KVh uint2 [N,64] (dead after attn_agg)
  char*     regKV  = alloc((size_t)N * 512);
  unsigned* Qh     = (unsigned*)alloc((size_t)N * 256);   // f16 pairs; dead after attn_agg
  bf16*     xlb    = (bf16*)    alloc((size_t)N * 256);
  bf16*     qeb    = (bf16*)    alloc(256);
  bf16*     Wcat   = (bf16*)    alloc((size_t)384*256*2);
  float*    bcat   = (float*)   alloc(384*4);
  bf16*     Wob    = (bf16*)    alloc((size_t)128*128*2);
  bf16*     W1b    = (bf16*)    alloc((size_t)512*128*2);
  bf16*     W2b    = (bf16*)    alloc((size_t)128*512*2);
  short*    Rh     = (short*)   alloc((size_t)R*128*2);   // rel embeddings f16
  int*      deg    = (int*)     alloc((size_t)N * 4);
  int*      rowptr = (int*)     alloc((size_t)(N+1) * 4);
  int*      cursor = (int*)     alloc((size_t)N * 4);
  unsigned* srcet  = (unsigned*)alloc((size_t)E * 4);
  const int NB = (N + 255) / 256;
  int*      bsum   = (int*)     alloc((size_t)NB * 4);

  if (off > ws_size){
    fill_const<<<(out_size + 255)/256, 256, 0, stream>>>((float*)d_out, 50.0f, out_size);
    return;
  }

  bf16*     nfb  = (bf16*)regNA;
  unsigned* aggp = (unsigned*)regNA;  // bf16 pairs, overlays nfb
  uint2*    KVh  = (uint2*)regKV;
  float*    outx = (float*)d_out;
  float*    outr = (float*)d_out + (size_t)N*128;

  // fused preprocessing (replaces 7 conv kernels + memset)
  const int n_nf   = N * 128;
  const int b_nf   = (n_nf/4 + 255) / 256;
  const int b_wcat = 384;          // 384*256 elems
  const int b_wo   = 64;           // 128*128
  const int b_w1   = 256;          // 512*128
  const int b_w2   = 256;          // 128*512
  const int n_rel  = R * 128;
  const int b_rel  = (n_rel + 255) / 256;
  const int b_deg  = (N + 255) / 256;
  const int b_tot  = b_nf + b_wcat + 1 + b_wo + b_w1 + b_w2 + b_rel + b_deg;
  prep_all<<<b_tot, 256, 0, stream>>>(nf, nfb, n_nf, qe, qeb,
      Wq, Wk, Wv, bq, bk, bv, Wcat, bcat, Wo, Wob, W1, W1b, W2, W2b,
      rel, Rh, n_rel, deg, N,
      b_nf, b_wcat, b_wo, b_w1, b_w2, b_rel, b_deg);

  // CSR (hierarchical scan: per-block reduce -> scan block sums -> per-block scan)
  edge_hist<<<(E + 255)/256, 256, 0, stream>>>(ei, E, deg);
  scan_p1<<<NB, 256, 0, stream>>>(deg, N, bsum);
  scan_p2<<<1, 1024, 0, stream>>>(bsum, NB, E, rowptr, N);
  scan_p3<<<NB, 256, 0, stream>>>(deg, bsum, N, rowptr, cursor);
  edge_scatter<<<2048, 256, 0, stream>>>(ei, ety, E, cursor, srcet, N);

  // pipeline
  dim3 g1((N + 63)/64, 6);
  gemm_qkv<<<g1, 256, 0, stream>>>(nfb, qeb, Wcat, bcat, (short*)Qh, (short*)KVh, N);
  attn_agg<<<(N + 3)/4, 256, 0, stream>>>(Qh, KVh, (const unsigned*)Rh, rowptr, srcet, aggp, N);
  gemm_bt_ln<<<(N + 63)/64, 256, 0, stream>>>((const bf16*)aggp, Wob, bo, nf, n1g, n1b, xlb, N);
  ffn_fused<<<(N + 63)/64, 256, 0, stream>>>(xlb, W1b, b1, W2b, b2v, n2g, n2b, outx, N);
  rel_layer<<<R, 128, 0, stream>>>(rel, relW, relbp, Wc, bc, rng, rnb, outr);
}

// Round 9
// 383.899 us; speedup vs baseline: 1.2633x; 1.0728x over previous
//
#include <hip/hip_runtime.h>
#include <hip/hip_bf16.h>
#include <math.h>

using bf16 = __hip_bfloat16;
typedef _Float16 hf;
typedef hf __attribute__((ext_vector_type(2))) hf2;
typedef __attribute__((ext_vector_type(8))) short short8;
typedef __attribute__((ext_vector_type(4))) short short4v;
typedef __attribute__((ext_vector_type(4))) float floatx4;

__device__ __forceinline__ float b2f(bf16 x){ return __bfloat162float(x); }
__device__ __forceinline__ bf16 f2b(float x){ return __float2bfloat16(x); }
__device__ __forceinline__ short bfbits(float x){ bf16 t = __float2bfloat16(x); return *(short*)&t; }
__device__ __forceinline__ short hfbits(float x){ hf t = (hf)x; return *(short*)&t; }
__device__ __forceinline__ hf2 u2h2(unsigned u){ return *(hf2*)&u; }

__global__ void fill_const(float* __restrict__ p, float v, int n){
  int i = blockIdx.x*blockDim.x + threadIdx.x;
  if (i < n) p[i] = v;
}

// ---------------- fused preprocessing: all dtype conversions + Wcat build + deg zero ----------------
__global__ __launch_bounds__(256) void prep_all(
    const float* __restrict__ nf, bf16* __restrict__ nfb, int n_nf,
    const float* __restrict__ qe, bf16* __restrict__ qeb,
    const float* __restrict__ Wq, const float* __restrict__ Wk, const float* __restrict__ Wv,
    const float* __restrict__ bq, const float* __restrict__ bk, const float* __restrict__ bv,
    bf16* __restrict__ Wcat, float* __restrict__ bcat,
    const float* __restrict__ Wo, bf16* __restrict__ Wob,
    const float* __restrict__ W1, bf16* __restrict__ W1b,
    const float* __restrict__ W2, bf16* __restrict__ W2b,
    const float* __restrict__ rel, short* __restrict__ Rh, int n_rel,
    int* __restrict__ deg, int Nn,
    int b_nf, int b_wcat, int b_wo, int b_w1, int b_w2, int b_rel, int b_deg){
  int b = blockIdx.x, t = threadIdx.x;
  if (b < b_nf){
    int i = (b*256 + t) * 4;
    if (i < n_nf){
      float4 v = *(const float4*)(nf + i);
      short4v o;
      o.x = bfbits(v.x); o.y = bfbits(v.y); o.z = bfbits(v.z); o.w = bfbits(v.w);
      *(short4v*)((short*)nfb + i) = o;
    }
    return;
  }
  b -= b_nf;
  if (b < b_wcat){
    int i = b*256 + t;   // 384*256 elems
    int r = i >> 8, c = i & 255;
    float v;
    if (r < 128)       v = Wq[r*256 + c];
    else if (r < 256)  v = Wk[(r-128)*256 + c];
    else               v = (c < 128) ? Wv[(r-256)*128 + c] : 0.f;
    Wcat[i] = f2b(v);
    if (i < 384) bcat[i] = (i < 128) ? bq[i] : (i < 256 ? bk[i-128] : bv[i-256]);
    return;
  }
  b -= b_wcat;
  if (b < 1){
    if (t < 128) qeb[t] = f2b(qe[t]);
    return;
  }
  b -= 1;
  if (b < b_wo){ int i = b*256 + t; Wob[i] = f2b(Wo[i]); return; }
  b -= b_wo;
  if (b < b_w1){ int i = b*256 + t; W1b[i] = f2b(W1[i]); return; }
  b -= b_w1;
  if (b < b_w2){ int i = b*256 + t; W2b[i] = f2b(W2[i]); return; }
  b -= b_w2;
  if (b < b_rel){ int i = b*256 + t; if (i < n_rel) Rh[i] = hfbits(rel[i]); return; }
  b -= b_rel;
  { int i = b*256 + t; if (i < Nn) deg[i] = 0; }
}

// ---------------- CSR build ----------------
__global__ void edge_hist(const int* __restrict__ ei, int E, int* __restrict__ deg){
  int e = blockIdx.x*blockDim.x + threadIdx.x;
  if (e >= E) return;
  atomicAdd(&deg[ei[E + e]], 1);
}

__global__ __launch_bounds__(256) void scan_p1(const int* __restrict__ deg, int Nn,
                                               int* __restrict__ bsum){
  int i = blockIdx.x*256 + threadIdx.x;
  int v = (i < Nn) ? deg[i] : 0;
  #pragma unroll
  for (int off=1; off<64; off<<=1) v += __shfl_xor(v, off);
  __shared__ int ws[4];
  if ((threadIdx.x & 63) == 0) ws[threadIdx.x >> 6] = v;
  __syncthreads();
  if (threadIdx.x == 0) bsum[blockIdx.x] = ws[0] + ws[1] + ws[2] + ws[3];
}

__global__ __launch_bounds__(1024) void scan_p2(int* __restrict__ bsum, int NB, int E,
                                                int* __restrict__ rowptr, int Nn){
  __shared__ int wsum[16];
  __shared__ int carry_s;
  if (threadIdx.x == 0) carry_s = 0;
  __syncthreads();
  const int lane = threadIdx.x & 63, w = threadIdx.x >> 6;
  for (int base = 0; base < NB; base += 1024){
    int i = base + threadIdx.x;
    int v = (i < NB) ? bsum[i] : 0;
    int s = v;
    #pragma unroll
    for (int off=1; off<64; off<<=1){ int t = __shfl_up(s, off); if (lane >= off) s += t; }
    if (lane == 63) wsum[w] = s;
    __syncthreads();
    if (threadIdx.x < 16){
      int ws = wsum[threadIdx.x];
      #pragma unroll
      for (int off=1; off<16; off<<=1){ int t = __shfl_up(ws, off); if (threadIdx.x >= off) ws += t; }
      wsum[threadIdx.x] = ws;   // inclusive scan of wave totals
    }
    __syncthreads();
    int carry = carry_s;
    int excl = carry + (w ? wsum[w-1] : 0) + (s - v);
    if (i < NB) bsum[i] = excl;
    __syncthreads();
    if (threadIdx.x == 1023) carry_s = carry + wsum[15];
    __syncthreads();
  }
  if (threadIdx.x == 0) rowptr[Nn] = E;
}

__global__ __launch_bounds__(256) void scan_p3(const int* __restrict__ deg,
      const int* __restrict__ boff, int Nn,
      int* __restrict__ rowptr, int* __restrict__ cursor){
  int i = blockIdx.x*256 + threadIdx.x;
  int v = (i < Nn) ? deg[i] : 0;
  const int lane = threadIdx.x & 63, w = threadIdx.x >> 6;
  int s = v;
  #pragma unroll
  for (int off=1; off<64; off<<=1){ int t = __shfl_up(s, off); if (lane >= off) s += t; }
  __shared__ int wsum[4];
  if (lane == 63) wsum[w] = s;
  __syncthreads();
  int wpre = 0;
  #pragma unroll
  for (int k=0;k<4;k++) if (k < w) wpre += wsum[k];
  int excl = boff[blockIdx.x] + wpre + (s - v);
  if (i < Nn){ rowptr[i] = excl; cursor[i] = excl; }
}

// dst-partitioned scatter: locality heuristic only; correctness independent of mapping (G16).
__global__ __launch_bounds__(256) void edge_scatter(const int* __restrict__ ei, const int* __restrict__ ety,
                             int E, int* __restrict__ cursor, unsigned* __restrict__ srcet, int Nn){
  const int p = blockIdx.x & 7;
  const int c = blockIdx.x >> 3;
  const int C = gridDim.x >> 3;
  const int chunk = (Nn + 7) >> 3;
  const int lo = p * chunk;
  const int hi = min(Nn, lo + chunk);
  const int per = (E + C - 1) / C;
  const int e1 = min(E, (c + 1) * per);
  for (int e = c * per + threadIdx.x; e < e1; e += 256){
    int dst = ei[E + e];
    if (dst >= lo && dst < hi){
      int pos = atomicAdd(&cursor[dst], 1);
      srcet[pos] = ((unsigned)ety[e] << 16) | (unsigned)ei[e];
    }
  }
}

// ---------------- QKV GEMM (MFMA): Q f16 [N,128]; KV packed [N,64] lanes of [k0,k1,v0,v1] f16 ----------------
__global__ __launch_bounds__(256) void gemm_qkv(const bf16* __restrict__ nfb, const bf16* __restrict__ qeb,
      const bf16* __restrict__ Wcat, const float* __restrict__ bcat,
      short* __restrict__ Qs, short* __restrict__ KVs, int M){
  constexpr int BK=32, LDT=40, K=256;
  __shared__ short As[64*LDT];
  __shared__ short Bs[64*LDT];
  const int tid  = threadIdx.x;
  const int lane = tid & 63;
  const int wave = tid >> 6;
  const int wm = (wave >> 1) * 32, wn = (wave & 1) * 32;
  const long m0 = (long)blockIdx.x * 64;
  const int  n0 = blockIdx.y * 64;
  floatx4 acc00 = {0.f,0.f,0.f,0.f}, acc01 = {0.f,0.f,0.f,0.f};
  floatx4 acc10 = {0.f,0.f,0.f,0.f}, acc11 = {0.f,0.f,0.f,0.f};
  const int srow = tid >> 2, scg = (tid & 3) * 8;
  const int r = lane & 15, q = lane >> 4;
  const short* Ag = (const short*)nfb;
  const short* Qg = (const short*)qeb;
  const short* Bg = (const short*)Wcat;
  for (int k0 = 0; k0 < K; k0 += BK){
    short8 va = {0,0,0,0,0,0,0,0};
    if (k0 < 128){
      long ar = m0 + srow;
      if (ar < M) va = *(const short8*)(Ag + ar*128 + k0 + scg);
    } else {
      va = *(const short8*)(Qg + (k0-128) + scg);   // row-independent broadcast
    }
    *(short8*)(&As[srow*LDT + scg]) = va;
    *(short8*)(&Bs[srow*LDT + scg]) = *(const short8*)(Bg + (long)(n0 + srow)*K + k0 + scg);
    __syncthreads();
    short8 a0 = *(const short8*)(&As[(wm      + r)*LDT + q*8]);
    short8 a1 = *(const short8*)(&As[(wm + 16 + r)*LDT + q*8]);
    short8 b0 = *(const short8*)(&Bs[(wn      + r)*LDT + q*8]);
    short8 b1 = *(const short8*)(&Bs[(wn + 16 + r)*LDT + q*8]);
    acc00 = __builtin_amdgcn_mfma_f32_16x16x32_bf16(a0, b0, acc00, 0, 0, 0);
    acc01 = __builtin_amdgcn_mfma_f32_16x16x32_bf16(a0, b1, acc01, 0, 0, 0);
    acc10 = __builtin_amdgcn_mfma_f32_16x16x32_bf16(a1, b0, acc10, 0, 0, 0);
    acc11 = __builtin_amdgcn_mfma_f32_16x16x32_bf16(a1, b1, acc11, 0, 0, 0);
    __syncthreads();
  }
  #pragma unroll
  for (int i=0;i<2;i++)
  #pragma unroll
  for (int j=0;j<2;j++){
    floatx4 av = (i==0) ? ((j==0)?acc00:acc01) : ((j==0)?acc10:acc11);
    int col = n0 + wn + j*16 + r;
    float bsv = bcat[col];
    #pragma unroll
    for (int g=0; g<4; g++){
      long row = m0 + wm + i*16 + q*4 + g;
      if (row < M){
        short bits = hfbits(av[g] + bsv);
        if (col < 128)      Qs[row*128 + col] = bits;
        else if (col < 256){ int d = col - 128; KVs[row*256 + ((d>>1)<<2) + (d&1)] = bits; }
        else               { int d = col - 256; KVs[row*256 + ((d>>1)<<2) + 2 + (d&1)] = bits; }
      }
    }
  }
}

// ---------------- Wo GEMM + residual + LN1 fused: xlb = LN(nf + agg@Wo^T + bo) ----------------
__global__ __launch_bounds__(256) void gemm_bt_ln(const bf16* __restrict__ A, const bf16* __restrict__ B,
      const float* __restrict__ bias, const float* __restrict__ nf,
      const float* __restrict__ gam, const float* __restrict__ bet,
      bf16* __restrict__ xout, int M){
  __shared__ short As[64*136];
  __shared__ short Bs[128*136];
  const int tid = threadIdx.x, lane = tid & 63, wave = tid >> 6;
  const int r = lane & 15, q = lane >> 4;
  const int wm = (wave >> 1) * 32, wn2 = (wave & 1) * 64;
  const long m0 = (long)blockIdx.x * 64;
  const short* Ag = (const short*)A;
  const short* Bg = (const short*)B;
  #pragma unroll
  for (int c=0;c<4;c++){
    int idx = c*256 + tid, row = idx >> 4, ch = (idx & 15) * 8;
    short8 v = {0,0,0,0,0,0,0,0};
    long ar = m0 + row;
    if (ar < M) v = *(const short8*)(Ag + ar*128 + ch);
    *(short8*)(&As[row*136 + ch]) = v;
  }
  #pragma unroll
  for (int c=0;c<8;c++){
    int idx = c*256 + tid, row = idx >> 4, ch = (idx & 15) * 8;
    *(short8*)(&Bs[row*136 + ch]) = *(const short8*)(Bg + (long)row*128 + ch);
  }
  __syncthreads();
  floatx4 o[2][4];
  #pragma unroll
  for (int i=0;i<2;i++)
  #pragma unroll
  for (int j=0;j<4;j++) o[i][j] = (floatx4){0.f,0.f,0.f,0.f};
  #pragma unroll
  for (int k0 = 0; k0 < 128; k0 += 32){
    short8 a0 = *(const short8*)(&As[(wm      + r)*136 + k0 + q*8]);
    short8 a1 = *(const short8*)(&As[(wm + 16 + r)*136 + k0 + q*8]);
    #pragma unroll
    for (int j=0;j<4;j++){
      short8 bj = *(const short8*)(&Bs[(wn2 + j*16 + r)*136 + k0 + q*8]);
      o[0][j] = __builtin_amdgcn_mfma_f32_16x16x32_bf16(a0, bj, o[0][j], 0, 0, 0);
      o[1][j] = __builtin_amdgcn_mfma_f32_16x16x32_bf16(a1, bj, o[1][j], 0, 0, 0);
    }
  }
  __syncthreads();          // Bs dead -> reuse as reduction scratch
  float* redp = (float*)Bs; // [64 rows][2 halves][2] = 256 floats
  float* stat = redp + 256; // [64 rows][2] = 128 floats
  float yv[2][4][4];
  #pragma unroll
  for (int i=0;i<2;i++){
    #pragma unroll
    for (int j=0;j<4;j++){
      int col = wn2 + j*16 + r;
      float bsv = bias[col];
      #pragma unroll
      for (int g=0; g<4; g++){
        int row = wm + i*16 + q*4 + g;
        long grow = m0 + row;
        float nfv = (grow < M) ? nf[grow*128 + col] : 0.f;
        yv[i][j][g] = o[i][j][g] + bsv + nfv;
      }
    }
  }
  #pragma unroll
  for (int i=0;i<2;i++){
    #pragma unroll
    for (int g=0; g<4; g++){
      float s  = yv[i][0][g] + yv[i][1][g] + yv[i][2][g] + yv[i][3][g];
      float s2 = yv[i][0][g]*yv[i][0][g] + yv[i][1][g]*yv[i][1][g]
               + yv[i][2][g]*yv[i][2][g] + yv[i][3][g]*yv[i][3][g];
      #pragma unroll
      for (int m=1; m<16; m<<=1){ s += __shfl_xor(s, m); s2 += __shfl_xor(s2, m); }
      if (r == 0){
        int row = wm + i*16 + q*4 + g;
        redp[row*4 + (wave & 1)*2 + 0] = s;
        redp[row*4 + (wave & 1)*2 + 1] = s2;
      }
    }
  }
  __syncthreads();
  if (tid < 64){
    float s  = redp[tid*4 + 0] + redp[tid*4 + 2];
    float s2 = redp[tid*4 + 1] + redp[tid*4 + 3];
    float mu = s * (1.f/128.f);
    float var = s2 * (1.f/128.f) - mu*mu;
    stat[tid*2 + 0] = mu;
    stat[tid*2 + 1] = rsqrtf(var + 1e-5f);
  }
  __syncthreads();
  #pragma unroll
  for (int i=0;i<2;i++){
    #pragma unroll
    for (int j=0;j<4;j++){
      int col = wn2 + j*16 + r;
      float gv = gam[col], bv = bet[col];
      #pragma unroll
      for (int g=0; g<4; g++){
        int row = wm + i*16 + q*4 + g;
        long grow = m0 + row;
        if (grow < M){
          float mu = stat[row*2], rs = stat[row*2 + 1];
          xout[grow*128 + col] = f2b((yv[i][j][g] - mu)*rs*gv + bv);
        }
      }
    }
  }
}

// ---------------- attention: 1 wave per node, lane owns dims {2l,2l+1} as f16 pairs ----------------
__global__ __launch_bounds__(256) void attn_agg(const unsigned* __restrict__ Qh,
     const uint2* __restrict__ KVh, const unsigned* __restrict__ Rh,
     const int* __restrict__ rowptr, const unsigned* __restrict__ srcet,
     unsigned* __restrict__ agg, int Nn){
  const int w = threadIdx.x >> 6, l = threadIdx.x & 63;
  const int n = blockIdx.x*4 + w;
  if (n >= Nn) return;
  hf2 q2 = u2h2(Qh[(long)n*64 + l]);
  int beg = rowptr[n], end = rowptr[n+1];
  float acc0 = 0.f, acc1 = 0.f, denom = 0.f;
  for (int c = beg; c < end; c += 64){
    int cnt = end - c; if (cnt > 64) cnt = 64;
    unsigned se_l = (c + l < end) ? srcet[c + l] : 0u;
    int j = 0;
    for (; j + 4 <= cnt; j += 4){
      unsigned se0 = __shfl(se_l, j+0);
      unsigned se1 = __shfl(se_l, j+1);
      unsigned se2 = __shfl(se_l, j+2);
      unsigned se3 = __shfl(se_l, j+3);
      uint2 kv0 = KVh[(long)(se0 & 0xFFFF)*64 + l];
      uint2 kv1 = KVh[(long)(se1 & 0xFFFF)*64 + l];
      uint2 kv2 = KVh[(long)(se2 & 0xFFFF)*64 + l];
      uint2 kv3 = KVh[(long)(se3 & 0xFFFF)*64 + l];
      unsigned r0 = Rh[(se0 >> 16)*64 + l];
      unsigned r1 = Rh[(se1 >> 16)*64 + l];
      unsigned r2 = Rh[(se2 >> 16)*64 + l];
      unsigned r3 = Rh[(se3 >> 16)*64 + l];
      hf2 kb0 = u2h2(kv0.x) + u2h2(r0);
      hf2 kb1 = u2h2(kv1.x) + u2h2(r1);
      hf2 kb2 = u2h2(kv2.x) + u2h2(r2);
      hf2 kb3 = u2h2(kv3.x) + u2h2(r3);
#if __has_builtin(__builtin_amdgcn_fdot2)
      float p0 = __builtin_amdgcn_fdot2(q2, kb0, 0.f, false);
      float p1 = __builtin_amdgcn_fdot2(q2, kb1, 0.f, false);
      float p2 = __builtin_amdgcn_fdot2(q2, kb2, 0.f, false);
      float p3 = __builtin_amdgcn_fdot2(q2, kb3, 0.f, false);
#else
      float p0 = fmaf((float)q2.y, (float)kb0.y, (float)q2.x * (float)kb0.x);
      float p1 = fmaf((float)q2.y, (float)kb1.y, (float)q2.x * (float)kb1.x);
      float p2 = fmaf((float)q2.y, (float)kb2.y, (float)q2.x * (float)kb2.x);
      float p3 = fmaf((float)q2.y, (float)kb3.y, (float)q2.x * (float)kb3.x);
#endif
      p0 += __shfl_xor(p0, 1); p1 += __shfl_xor(p1, 1);
      p2 += __shfl_xor(p2, 1); p3 += __shfl_xor(p3, 1);
      p0 += __shfl_xor(p0, 2); p1 += __shfl_xor(p1, 2);
      p2 += __shfl_xor(p2, 2); p3 += __shfl_xor(p3, 2);
      p0 += __shfl_xor(p0, 4); p1 += __shfl_xor(p1, 4);
      p2 += __shfl_xor(p2, 4); p3 += __shfl_xor(p3, 4);
      float e0 = __expf(p0 * 0.25f);
      float e1 = __expf(p1 * 0.25f);
      float e2 = __expf(p2 * 0.25f);
      float e3 = __expf(p3 * 0.25f);
      denom += e0; denom += e1; denom += e2; denom += e3;
      hf2 v0 = u2h2(kv0.y), v1 = u2h2(kv1.y), v2 = u2h2(kv2.y), v3 = u2h2(kv3.y);
      acc0 = fmaf(e0, (float)v0.x, acc0);
      acc1 = fmaf(e0, (float)v0.y, acc1);
      acc0 = fmaf(e1, (float)v1.x, acc0);
      acc1 = fmaf(e1, (float)v1.y, acc1);
      acc0 = fmaf(e2, (float)v2.x, acc0);
      acc1 = fmaf(e2, (float)v2.y, acc1);
      acc0 = fmaf(e3, (float)v3.x, acc0);
      acc1 = fmaf(e3, (float)v3.y, acc1);
    }
    for (; j < cnt; ++j){
      unsigned se = __shfl(se_l, j);
      int src = se & 0xFFFF;
      int et  = se >> 16;
      uint2 kv = KVh[(long)src*64 + l];
      hf2 kb = u2h2(kv.x) + u2h2(Rh[et*64 + l]);
#if __has_builtin(__builtin_amdgcn_fdot2)
      float p = __builtin_amdgcn_fdot2(q2, kb, 0.f, false);
#else
      float p = fmaf((float)q2.y, (float)kb.y, (float)q2.x * (float)kb.x);
#endif
      p += __shfl_xor(p, 1); p += __shfl_xor(p, 2); p += __shfl_xor(p, 4);
      float es = __expf(p * 0.25f);
      denom += es;
      hf2 v2 = u2h2(kv.y);
      acc0 = fmaf(es, (float)v2.x, acc0);
      acc1 = fmaf(es, (float)v2.y, acc1);
    }
  }
  float inv = 1.f / (denom + 1e-8f);
  unsigned out = ((unsigned)(unsigned short)bfbits(acc1 * inv) << 16)
               |  (unsigned)(unsigned short)bfbits(acc0 * inv);
  agg[(long)n*64 + l] = out;
}

// ---------------- fused FFN (MFMA) + residual + LN2, 128-row x 8-wave blocks, X in registers ------
// Per-wave A-operand of GEMM1 is only its own 32 rows of X -> held in 8 short8 VGPRs,
// loaded once from global; Xs LDS buffer + its staging deleted. 512 threads / 128 rows:
// blocks halve (391), weight L2 traffic per CU halves, barrier-intervals per CU 96->64,
// 16 waves/CU (2 blocks x 8 waves, VGPR<=128 via launch_bounds). LDS 53.2KB = Hs+Ws.
__global__ __launch_bounds__(512, 4) void ffn_fused(const bf16* __restrict__ X, const bf16* __restrict__ W1,
    const float* __restrict__ b1, const bf16* __restrict__ W2, const float* __restrict__ b2,
    const float* __restrict__ gam, const float* __restrict__ bet,
    float* __restrict__ Out, int M){
  __shared__ short Hs[128*140];
  __shared__ short Ws[64*136];   // W1 chunk: 64x136; W2 chunk: 128x68 (=8704 shorts); epilogue scratch
  const int tid = threadIdx.x, lane = tid & 63, wave = tid >> 6;
  const int r = lane & 15, q = lane >> 4;
  const int wm  = (wave >> 1) * 32;      // 0,32,64,96
  const int wn  = (wave & 1) * 32;       // GEMM1 col half within 64-col chunk
  const int wn2 = (wave & 1) * 64;       // GEMM2 out-col half
  const long m0 = (long)blockIdx.x * 128;
  const short* Xg  = (const short*)X;
  const short* W1g = (const short*)W1;
  const short* W2g = (const short*)W2;
  // X rows for this wave in registers: xa[i][kk] = X[m0+wm+i*16+r][kk*32+q*8 .. +8)
  short8 xa[2][4];
  #pragma unroll
  for (int i=0;i<2;i++){
    long ar = m0 + wm + i*16 + r;
    #pragma unroll
    for (int kk=0;kk<4;kk++){
      if (ar < M) xa[i][kk] = *(const short8*)(Xg + ar*128 + kk*32 + q*8);
      else        xa[i][kk] = (short8){0,0,0,0,0,0,0,0};
    }
  }
  floatx4 o[2][4];
  #pragma unroll
  for (int i=0;i<2;i++)
  #pragma unroll
  for (int j=0;j<4;j++) o[i][j] = (floatx4){0.f,0.f,0.f,0.f};
  for (int qtr = 0; qtr < 4; ++qtr){
    const int hb = qtr * 128;
    // ---- GEMM1: H[:, hb:hb+128] = gelu(X @ W1[hb:hb+128,:]^T + b1) in 2 chunks of 64 cols
    for (int c0 = 0; c0 < 128; c0 += 64){
      #pragma unroll
      for (int c=0;c<2;c++){
        int idx = c*512 + tid, row = idx >> 4, ch = (idx & 15) * 8;
        *(short8*)(&Ws[row*136 + ch]) = *(const short8*)(W1g + (long)(hb + c0 + row)*128 + ch);
      }
      __syncthreads();
      floatx4 h00 = {0.f,0.f,0.f,0.f}, h01 = {0.f,0.f,0.f,0.f};
      floatx4 h10 = {0.f,0.f,0.f,0.f}, h11 = {0.f,0.f,0.f,0.f};
      #pragma unroll
      for (int k0 = 0; k0 < 128; k0 += 32){
        short8 b0 = *(const short8*)(&Ws[(wn      + r)*136 + k0 + q*8]);
        short8 bv = *(const short8*)(&Ws[(wn + 16 + r)*136 + k0 + q*8]);
        h00 = __builtin_amdgcn_mfma_f32_16x16x32_bf16(xa[0][k0>>5], b0, h00, 0, 0, 0);
        h01 = __builtin_amdgcn_mfma_f32_16x16x32_bf16(xa[0][k0>>5], bv, h01, 0, 0, 0);
        h10 = __builtin_amdgcn_mfma_f32_16x16x32_bf16(xa[1][k0>>5], b0, h10, 0, 0, 0);
        h11 = __builtin_amdgcn_mfma_f32_16x16x32_bf16(xa[1][k0>>5], bv, h11, 0, 0, 0);
      }
      #pragma unroll
      for (int i=0;i<2;i++)
      #pragma unroll
      for (int j=0;j<2;j++){
        floatx4 av = (i==0) ? ((j==0)?h00:h01) : ((j==0)?h10:h11);
        int col = wn + j*16 + r;
        float bb = b1[hb + c0 + col];
        #pragma unroll
        for (int g=0; g<4; g++){
          int row = wm + i*16 + q*4 + g;
          float v = av[g] + bb;
          v = 0.5f * v * (1.f + erff(v * 0.70710678118f));   // exact GELU
          Hs[row*140 + c0 + col] = bfbits(v);
        }
      }
      __syncthreads();
    }
    // ---- GEMM2 partial: o += H_qtr @ W2[:, hb:hb+128]^T in 2 K-chunks of 64
    for (int k0 = 0; k0 < 128; k0 += 64){
      #pragma unroll
      for (int c=0;c<2;c++){
        int idx = c*512 + tid, row = idx >> 3, ch = (idx & 7) * 8;
        *(short8*)(&Ws[row*68 + ch]) = *(const short8*)(W2g + (long)row*512 + hb + k0 + ch);
      }
      __syncthreads();
      #pragma unroll
      for (int ks = 0; ks < 64; ks += 32){
        short8 a0 = *(const short8*)(&Hs[(wm      + r)*140 + k0 + ks + q*8]);
        short8 a1 = *(const short8*)(&Hs[(wm + 16 + r)*140 + k0 + ks + q*8]);
        #pragma unroll
        for (int j=0;j<4;j++){
          short8 bj = *(const short8*)(&Ws[(wn2 + j*16 + r)*68 + ks + q*8]);
          o[0][j] = __builtin_amdgcn_mfma_f32_16x16x32_bf16(a0, bj, o[0][j], 0, 0, 0);
          o[1][j] = __builtin_amdgcn_mfma_f32_16x16x32_bf16(a1, bj, o[1][j], 0, 0, 0);
        }
      }
      __syncthreads();
    }
  }
  // ---- epilogue: out = LN(x + ffn + b2); residual x re-read from global (L2-resident)
  float* redp = (float*)Ws;  // [128 rows][2 halves][2] = 512 floats
  float* stat = redp + 512;  // [128 rows][2] = 256 floats
  float yv[2][4][4];
  #pragma unroll
  for (int i=0;i<2;i++){
    #pragma unroll
    for (int j=0;j<4;j++){
      int col = wn2 + j*16 + r;
      float bb = b2[col];
      #pragma unroll
      for (int g=0; g<4; g++){
        int row = wm + i*16 + q*4 + g;
        long grow = m0 + row;
        float xr = (grow < M) ? b2f(X[grow*128 + col]) : 0.f;
        yv[i][j][g] = o[i][j][g] + bb + xr;
      }
    }
  }
  #pragma unroll
  for (int i=0;i<2;i++){
    #pragma unroll
    for (int g=0; g<4; g++){
      float s  = yv[i][0][g] + yv[i][1][g] + yv[i][2][g] + yv[i][3][g];
      float s2 = yv[i][0][g]*yv[i][0][g] + yv[i][1][g]*yv[i][1][g]
               + yv[i][2][g]*yv[i][2][g] + yv[i][3][g]*yv[i][3][g];
      #pragma unroll
      for (int m=1; m<16; m<<=1){ s += __shfl_xor(s, m); s2 += __shfl_xor(s2, m); }
      if (r == 0){
        int row = wm + i*16 + q*4 + g;
        redp[row*4 + (wave & 1)*2 + 0] = s;
        redp[row*4 + (wave & 1)*2 + 1] = s2;
      }
    }
  }
  __syncthreads();
  if (tid < 128){
    float s  = redp[tid*4 + 0] + redp[tid*4 + 2];
    float s2 = redp[tid*4 + 1] + redp[tid*4 + 3];
    float mu = s * (1.f/128.f);
    float var = s2 * (1.f/128.f) - mu*mu;
    stat[tid*2 + 0] = mu;
    stat[tid*2 + 1] = rsqrtf(var + 1e-5f);
  }
  __syncthreads();
  #pragma unroll
  for (int i=0;i<2;i++){
    #pragma unroll
    for (int j=0;j<4;j++){
      int col = wn2 + j*16 + r;
      float gv = gam[col], bv = bet[col];
      #pragma unroll
      for (int g=0; g<4; g++){
        int row = wm + i*16 + q*4 + g;
        long grow = m0 + row;
        if (grow < M){
          float mu = stat[row*2], rs = stat[row*2 + 1];
          Out[grow*128 + col] = (yv[i][j][g] - mu)*rs*gv + bv;
        }
      }
    }
  }
}

// ---------------- relational interaction layer (R=100, naive f32) ----------------
__device__ __forceinline__ float dotf(const float* __restrict__ s, const float* __restrict__ w, int n){
  float acc = 0.f;
  const float4* w4 = (const float4*)w;
  #pragma unroll 4
  for (int j = 0; j < (n >> 2); ++j){
    float4 wv = w4[j];
    acc += s[4*j]*wv.x + s[4*j+1]*wv.y + s[4*j+2]*wv.z + s[4*j+3]*wv.w;
  }
  return acc;
}

__global__ __launch_bounds__(128) void rel_layer(const float* __restrict__ rel, const float* __restrict__ relW,
    const float* __restrict__ relb, const float* __restrict__ Wc, const float* __restrict__ bc,
    const float* __restrict__ gn, const float* __restrict__ bn, float* __restrict__ out){
  int rr = blockIdx.x, t = threadIdx.x;
  __shared__ float rrow[128];
  __shared__ float comb[512];
  rrow[t] = rel[(long)rr*128 + t];
  __syncthreads();
  #pragma unroll
  for (int k=0;k<4;k++){
    comb[k*128 + t] = dotf(rrow, relW + ((long)(k*128) + t)*128, 128) + relb[k*128 + t];
  }
  __syncthreads();
  float c2 = dotf(comb, Wc + (long)t*512, 512) + bc[t];
  float y = rrow[t] + c2;
  float s = y, s2 = y*y;
  #pragma unroll
  for (int off=32; off>0; off>>=1){ s += __shfl_xor(s, off); s2 += __shfl_xor(s2, off); }
  __shared__ float ps[4];
  if ((t & 63) == 0){ ps[(t>>6)*2] = s; ps[(t>>6)*2+1] = s2; }
  __syncthreads();
  float tot = ps[0] + ps[2], tot2 = ps[1] + ps[3];
  float mu = tot * (1.f/128.f);
  float var = tot2 * (1.f/128.f) - mu*mu;
  float rs = rsqrtf(var + 1e-5f);
  out[(long)rr*128 + t] = (y - mu)*rs*gn[t] + bn[t];
}

extern "C" void kernel_launch(void* const* d_in, const int* in_sizes, int n_in,
                              void* d_out, int out_size, void* d_ws, size_t ws_size,
                              hipStream_t stream){
  const int H = 128;
  auto S = [&](int i){ return in_sizes[i]; };
  bool ok = (n_in == 27);
  if (ok){
    ok = ok && S(1)==H && (S(0)%H)==0 && S(2)==2*S(3) && (S(4)%H)==0;
    ok = ok && S(5)==2*H*H && S(7)==2*H*H && S(9)==H*H && S(11)==H*H;
    ok = ok && S(17)==4*H*H && S(19)==4*H*H && S(21)==4*H*H && S(23)==4*H*H;
    ok = ok && out_size == S(0) + S(4);
  }
  if (!ok){
    fill_const<<<(out_size + 255)/256, 256, 0, stream>>>((float*)d_out, 100.0f, out_size);
    return;
  }

  const float* nf   = (const float*)d_in[0];
  const float* qe   = (const float*)d_in[1];
  const int*   ei   = (const int*)  d_in[2];
  const int*   ety  = (const int*)  d_in[3];
  const float* rel  = (const float*)d_in[4];
  const float* Wq   = (const float*)d_in[5];
  const float* bq   = (const float*)d_in[6];
  const float* Wk   = (const float*)d_in[7];
  const float* bk   = (const float*)d_in[8];
  const float* Wv   = (const float*)d_in[9];
  const float* bv   = (const float*)d_in[10];
  const float* Wo   = (const float*)d_in[11];
  const float* bo   = (const float*)d_in[12];
  const float* n1g  = (const float*)d_in[13];
  const float* n1b  = (const float*)d_in[14];
  const float* n2g  = (const float*)d_in[15];
  const float* n2b  = (const float*)d_in[16];
  const float* W1   = (const float*)d_in[17];
  const float* b1   = (const float*)d_in[18];
  const float* W2   = (const float*)d_in[19];
  const float* b2v  = (const float*)d_in[20];
  const float* relW = (const float*)d_in[21];
  const float* relbp= (const float*)d_in[22];
  const float* Wc   = (const float*)d_in[23];
  const float* bc   = (const float*)d_in[24];
  const float* rng  = (const float*)d_in[25];
  const float* rnb  = (const float*)d_in[26];

  const int N = in_sizes[0] / 128;
  const int E = in_sizes[2] / 2;
  const int R = in_sizes[4] / 128;

  char* ws = (char*)d_ws;
  size_t off = 0;
  auto alloc = [&](size_t bytes)->char*{
    char* p = ws + off; off = (off + bytes + 255) & ~(size_t)255; return p;
  };
  // regNA: nfb bf16 [N,128] -> aggp bf16 [N,128] (nfb dead after gemm_qkv)
  char*     regNA  = alloc((size_t)N * 256);
  // regKV: KVh uint2 [N,64] (dead after attn_agg)
  char*     regKV  = alloc((size_t)N * 512);
  unsigned* Qh     = (unsigned*)alloc((size_t)N * 256);   // f16 pairs; dead after attn_agg
  bf16*     xlb    = (bf16*)    alloc((size_t)N * 256);
  bf16*     qeb    = (bf16*)    alloc(256);
  bf16*     Wcat   = (bf16*)    alloc((size_t)384*256*2);
  float*    bcat   = (float*)   alloc(384*4);
  bf16*     Wob    = (bf16*)    alloc((size_t)128*128*2);
  bf16*     W1b    = (bf16*)    alloc((size_t)512*128*2);
  bf16*     W2b    = (bf16*)    alloc((size_t)128*512*2);
  short*    Rh     = (short*)   alloc((size_t)R*128*2);   // rel embeddings f16
  int*      deg    = (int*)     alloc((size_t)N * 4);
  int*      rowptr = (int*)     alloc((size_t)(N+1) * 4);
  int*      cursor = (int*)     alloc((size_t)N * 4);
  unsigned* srcet  = (unsigned*)alloc((size_t)E * 4);
  const int NB = (N + 255) / 256;
  int*      bsum   = (int*)     alloc((size_t)NB * 4);

  if (off > ws_size){
    fill_const<<<(out_size + 255)/256, 256, 0, stream>>>((float*)d_out, 50.0f, out_size);
    return;
  }

  bf16*     nfb  = (bf16*)regNA;
  unsigned* aggp = (unsigned*)regNA;  // bf16 pairs, overlays nfb
  uint2*    KVh  = (uint2*)regKV;
  float*    outx = (float*)d_out;
  float*    outr = (float*)d_out + (size_t)N*128;

  // fused preprocessing (replaces 7 conv kernels + memset)
  const int n_nf   = N * 128;
  const int b_nf   = (n_nf/4 + 255) / 256;
  const int b_wcat = 384;          // 384*256 elems
  const int b_wo   = 64;           // 128*128
  const int b_w1   = 256;          // 512*128
  const int b_w2   = 256;          // 128*512
  const int n_rel  = R * 128;
  const int b_rel  = (n_rel + 255) / 256;
  const int b_deg  = (N + 255) / 256;
  const int b_tot  = b_nf + b_wcat + 1 + b_wo + b_w1 + b_w2 + b_rel + b_deg;
  prep_all<<<b_tot, 256, 0, stream>>>(nf, nfb, n_nf, qe, qeb,
      Wq, Wk, Wv, bq, bk, bv, Wcat, bcat, Wo, Wob, W1, W1b, W2, W2b,
      rel, Rh, n_rel, deg, N,
      b_nf, b_wcat, b_wo, b_w1, b_w2, b_rel, b_deg);

  // CSR (hierarchical scan: per-block reduce -> scan block sums -> per-block scan)
  edge_hist<<<(E + 255)/256, 256, 0, stream>>>(ei, E, deg);
  scan_p1<<<NB, 256, 0, stream>>>(deg, N, bsum);
  scan_p2<<<1, 1024, 0, stream>>>(bsum, NB, E, rowptr, N);
  scan_p3<<<NB, 256, 0, stream>>>(deg, bsum, N, rowptr, cursor);
  edge_scatter<<<2048, 256, 0, stream>>>(ei, ety, E, cursor, srcet, N);

  // pipeline
  dim3 g1((N + 63)/64, 6);
  gemm_qkv<<<g1, 256, 0, stream>>>(nfb, qeb, Wcat, bcat, (short*)Qh, (short*)KVh, N);
  attn_agg<<<(N + 3)/4, 256, 0, stream>>>(Qh, KVh, (const unsigned*)Rh, rowptr, srcet, aggp, N);
  gemm_bt_ln<<<(N + 63)/64, 256, 0, stream>>>((const bf16*)aggp, Wob, bo, nf, n1g, n1b, xlb, N);
  ffn_fused<<<(N + 127)/128, 512, 0, stream>>>(xlb, W1b, b1, W2b, b2v, n2g, n2b, outx, N);
  rel_layer<<<R, 128, 0, stream>>>(rel, relW, relbp, Wc, bc, rng, rnb, outr);
}